// Round 9
// baseline (327.244 us; speedup 1.0000x reference)
//
#include <hip/hip_runtime.h>

typedef __attribute__((ext_vector_type(8))) short bf16x8;
typedef __attribute__((ext_vector_type(4))) float f32x4;
typedef __attribute__((ext_vector_type(2))) long long ll2;
using u16 = unsigned short;
using u8 = unsigned char;

#define DEVINL static __device__ __forceinline__

DEVINL u16 f2bf(float f) {
  union { float f; unsigned u; } v; v.f = f;
  unsigned r = v.u + 0x7FFFu + ((v.u >> 16) & 1u);   // RNE
  return (u16)(r >> 16);
}

// fp32 -> OCP e4m3fn, RNE, saturating, denormal-aware
DEVINL u8 f2e4m3(float f) {
  union { float f; unsigned u; } v; v.f = f;
  unsigned s = (v.u >> 24) & 0x80u;
  float a = fabsf(f);
  a = fminf(a, 448.f);
  union { float f; unsigned u; } b; b.f = a;
  unsigned bu = b.u + 0x7FFFFu + ((b.u >> 20) & 1u);   // RNE at bit 20
  unsigned e = bu >> 23;
  unsigned r;
  if (e >= 121) {                       // normal (>= 2^-6)
    r = ((e - 120) << 3) | ((bu >> 20) & 7u);
    if (r > 0x7Eu) r = 0x7Eu;
  } else {                              // denormal: round(a * 512)
    r = (unsigned)(a * 512.f + 0.5f);
    if (r > 7u) r = 8u;                 // bumps to min normal
  }
  return (u8)(r | s);
}

DEVINL void gload16(const u16* g, u16* l) {
  __builtin_amdgcn_global_load_lds((const __attribute__((address_space(1))) void*)g,
                                   (__attribute__((address_space(3))) void*)l,
                                   16, 0, 0);
}
DEVINL void gload16b(const u8* g, u8* l) {
  __builtin_amdgcn_global_load_lds((const __attribute__((address_space(1))) void*)g,
                                   (__attribute__((address_space(3))) void*)l,
                                   16, 0, 0);
}

// ---------------- GroupNorm stats: two-stage, 512-block parallel ----------------
__global__ __launch_bounds__(256) void gn_stats1_k(const float* __restrict__ x,
                                                   float* __restrict__ psum,
                                                   float* __restrict__ psumsq) {
  const int blk = blockIdx.x;
  const float4* p4 = (const float4*)(x + (size_t)(blk >> 4) * (64 * 4096))
                     + (size_t)(blk & 15) * 4096;
  float s = 0.f, ss = 0.f;
  #pragma unroll
  for (int i = 0; i < 16; ++i) {
    float4 v = p4[i*256 + threadIdx.x];
    s  += v.x + v.y + v.z + v.w;
    ss += v.x*v.x + v.y*v.y + v.z*v.z + v.w*v.w;
  }
  #pragma unroll
  for (int off = 32; off > 0; off >>= 1) {
    s  += __shfl_down(s, off, 64);
    ss += __shfl_down(ss, off, 64);
  }
  __shared__ float rs[4], rss[4];
  const int lane = threadIdx.x & 63, w = threadIdx.x >> 6;
  if (lane == 0) { rs[w] = s; rss[w] = ss; }
  __syncthreads();
  if (threadIdx.x == 0) {
    psum[blk]   = rs[0]+rs[1]+rs[2]+rs[3];
    psumsq[blk] = rss[0]+rss[1]+rss[2]+rss[3];
  }
}

__global__ void gn_stats2_k(const float* __restrict__ psum,
                            const float* __restrict__ psumsq,
                            float* __restrict__ stats) {
  const int bg = threadIdx.x;   // 32 threads
  if (bg >= 32) return;
  float s = 0.f, ss = 0.f;
  #pragma unroll
  for (int p = 0; p < 16; ++p) { s += psum[bg*16+p]; ss += psumsq[bg*16+p]; }
  const float inv = 1.f / 262144.f;
  float mean = s * inv;
  float var  = ss * inv - mean * mean;
  stats[bg*2]   = mean;
  stats[bg*2+1] = rsqrtf(var + 1e-5f);
}

// Normalize + transpose: x[b][c][n] -> hT[b][n][c] bf16.
__global__ __launch_bounds__(256) void gn_apply_k(const float* __restrict__ x,
                                                  const float* __restrict__ gamma,
                                                  const float* __restrict__ beta,
                                                  const float* __restrict__ stats,
                                                  u16* __restrict__ hT) {
  __shared__ u16 tile[64][65];
  const int b = blockIdx.z, ct = blockIdx.y, nt = blockIdx.x;
  const int t = threadIdx.x;
  const float mean = stats[(b*8 + ct)*2 + 0];
  const float rstd = stats[(b*8 + ct)*2 + 1];
  const float* xb = x + ((size_t)b*512 + (size_t)ct*64) * 4096 + nt*64;
  #pragma unroll
  for (int i = 0; i < 16; ++i) {
    int idx = i*256 + t; int cl = idx >> 6, nl = idx & 63;
    float v  = xb[(size_t)cl*4096 + nl];
    float hn = (v - mean) * rstd * gamma[ct*64 + cl] + beta[ct*64 + cl];
    tile[cl][nl] = f2bf(hn);
  }
  __syncthreads();
  u16* o = hT + ((size_t)b*4096 + (size_t)nt*64) * 512 + ct*64;
  #pragma unroll
  for (int i = 0; i < 16; ++i) {
    int idx = i*256 + t; int nl = idx >> 6, cl = idx & 63;
    o[(size_t)nl*512 + cl] = tile[cl][nl];
  }
}

__global__ __launch_bounds__(256) void cast_w_k(const float* __restrict__ wq,
                                                const float* __restrict__ wp,
                                                u16* __restrict__ wqb,
                                                u16* __restrict__ wpb) {
  int i = blockIdx.x*256 + threadIdx.x;
  if (i < 1536*512) wqb[i] = f2bf(wq[i]);
  if (i < 512*512)  wpb[i] = f2bf(wp[i]);
}

// ---------------- NT GEMM core (m97 structure, 128x128, 4 waves) ----------------
DEVINL void gemm_nt_core(const u16* __restrict__ A, int lda,
                         const u16* __restrict__ B, int ldb,
                         int K, u16* As, u16* Bs, f32x4 acc[4][4]) {
  const int tid = threadIdx.x;
  const int lane = tid & 63, w = tid >> 6;
  const int wr = w >> 1, wc = w & 1;
  const int fr = lane & 15, fk = lane >> 4;
  for (int kt = 0; kt < K; kt += 64) {
    #pragma unroll
    for (int i = 0; i < 4; ++i) {
      int ch = i*256 + tid;
      int row = ch >> 3, kc = ch & 7;
      gload16(A + (size_t)row*lda + kt + kc*8, As + ch*8);
      gload16(B + (size_t)row*ldb + kt + kc*8, Bs + ch*8);
    }
    __syncthreads();
    #pragma unroll
    for (int kk = 0; kk < 2; ++kk) {
      bf16x8 af[4], bfg[4];
      #pragma unroll
      for (int i = 0; i < 4; ++i)
        af[i] = *(const bf16x8*)(As + ((wr*64 + i*16 + fr)*64 + kk*32 + fk*8));
      #pragma unroll
      for (int j = 0; j < 4; ++j)
        bfg[j] = *(const bf16x8*)(Bs + ((wc*64 + j*16 + fr)*64 + kk*32 + fk*8));
      #pragma unroll
      for (int i = 0; i < 4; ++i)
        #pragma unroll
        for (int j = 0; j < 4; ++j)
          acc[i][j] = __builtin_amdgcn_mfma_f32_16x16x32_bf16(af[i], bfg[j], acc[i][j], 0, 0, 0);
    }
    __syncthreads();
  }
}

#define GEMM_PROLOGUE() \
  __shared__ __align__(16) u16 As[128*64]; \
  __shared__ __align__(16) u16 Bs[128*64]; \
  f32x4 acc[4][4] = {}; \
  const int tid = threadIdx.x; \
  const int lane = tid & 63, w = tid >> 6; \
  const int wr = w >> 1, wc = w & 1; \
  const int fr = lane & 15, fk = lane >> 4; \
  (void)lane;

// QKV. useF8: q,k stored as fp8 e4m3 (for the fp8 scores path); else bf16.
__global__ __launch_bounds__(256) void k_qkv(const u16* __restrict__ hT,
                                             const u16* __restrict__ wq,
                                             const float* __restrict__ bqkv,
                                             u16* __restrict__ qT, u16* __restrict__ kT,
                                             u16* __restrict__ vb,
                                             u8* __restrict__ qF8, u8* __restrict__ kF8,
                                             int useF8) {
  GEMM_PROLOGUE();
  const int bz = blockIdx.z;
  const int rowBase = blockIdx.y * 128, colBase = blockIdx.x * 128;
  gemm_nt_core(hT + ((size_t)bz*4096 + rowBase)*512, 512,
               wq + (size_t)colBase*512, 512, 512, As, Bs, acc);
  #pragma unroll
  for (int i = 0; i < 4; ++i)
    #pragma unroll
    for (int j = 0; j < 4; ++j)
      #pragma unroll
      for (int r = 0; r < 4; ++r) {
        int n = rowBase + wr*64 + i*16 + fk*4 + r;
        int o = colBase + wc*64 + j*16 + fr;
        float val = acc[i][j][r] + bqkv[o];
        if (useF8) {
          if (o < 512)       qF8[((size_t)bz*4096 + n)*512 + o]         = f2e4m3(val);
          else if (o < 1024) kF8[((size_t)bz*4096 + n)*512 + (o - 512)] = f2e4m3(val);
          else               vb[((size_t)bz*512 + (o - 1024))*4096 + n] = f2bf(val);
        } else {
          u16 u = f2bf(val);
          if (o < 512)       qT[((size_t)bz*4096 + n)*512 + o]          = u;
          else if (o < 1024) kT[((size_t)bz*4096 + n)*512 + (o - 512)]  = u;
          else               vb[((size_t)bz*512 + (o - 1024))*4096 + n] = u;
        }
      }
}

// ------------- Scores (fp8): 256x256, BK=64, 4-phase counted-vmcnt --------------
// Loop = round-7 skeleton; B-plane swizzle period (row>>2)&1 both sides.
// Epilogue: two 64-row passes; per-wave 8KB LDS transpose tile (group-XOR
// swizzle) -> E written as dwordx4 full-line stores. Total LDS stays 64KB.
DEVINL void stageA_f8(const u8* __restrict__ src, int kofs, u8* plane, int tid) {
  #pragma unroll
  for (int q = 0; q < 2; ++q) {
    int c = q*512 + tid;
    int row = c >> 2, s16 = c & 3;
    int s16s = s16 ^ ((row >> 1) & 3);
    gload16b(src + (size_t)row*512 + kofs + s16s*16, plane + c*16);
  }
}
DEVINL void stageB_f8(const u8* __restrict__ src, int kofs, u8* plane, int tid) {
  int row = tid >> 1, s16 = tid & 1;
  int s16s = s16 ^ ((row >> 2) & 1);   // period-8 -> 2-way (free)
  gload16b(src + (size_t)row*512 + kofs + s16s*16, plane + tid*16);
}

#define MFMA8(a, b, c) __builtin_amdgcn_mfma_f32_16x16x32_fp8_fp8((a), (b), (c), 0, 0, 0)

__global__ __launch_bounds__(512) void k_scores256_f8(const u8* __restrict__ qF8,
                                                      const u8* __restrict__ kF8,
                                                      u16* __restrict__ E,
                                                      float* __restrict__ lsum) {
  __shared__ __align__(16) u8 lds_all[65536];      // GEMM bufs / epilogue tiles
  u8* Af0 = lds_all;                               // [2][256*64]  (32 KB)
  u8* Bf0 = lds_all + 32768;                       // [2][2][256*32] (32 KB)
  f32x4 acc[8][4] = {};
  const int tid = threadIdx.x;
  const int lane = tid & 63, w = tid >> 6;
  const int wr = w >> 2, wc = w & 3;               // 2M x 4N wave grid
  const int fr = lane & 15, fk = lane >> 4;
  const int bz = blockIdx.z;
  // T1: bijective XCD swizzle (256 blocks/slice, 32 per XCD, grouped by Q-row)
  int f = blockIdx.y * 16 + blockIdx.x;
  int L = (f & 7) * 32 + (f >> 3);
  const int rowBase = (L >> 4) * 256, colBase = (L & 15) * 256;
  const u8* qa = qF8 + (size_t)bz*4096*512 + (size_t)rowBase*512;
  const u8* ka = kF8 + (size_t)bz*4096*512 + (size_t)colBase*512;
  u16* Eb = E + (size_t)bz*4096*4096;
  float* ls = lsum + (size_t)bz*4096;

  // prologue: tile 0 units; vmcnt(1) -> A(0), B0(0) landed (B1(0) may fly)
  stageA_f8(qa, 0,  Af0, tid);
  stageB_f8(ka, 0,  Bf0, tid);
  stageB_f8(ka, 32, Bf0 + 8192, tid);     // B1(0) = Bf[0][1]  (round-8 bug fixed)
  asm volatile("s_waitcnt vmcnt(1)" ::: "memory");
  __builtin_amdgcn_s_barrier();

  #pragma unroll 1
  for (int t = 0; t < 8; ++t) {
    const int cur = t & 1, nxt = cur ^ 1;
    const int ktn = ((t + 1) & 7) * 64;           // wrap: last tile stages dummy
    const u8* Ap = Af0 + cur*16384;
    const u8* B0 = Bf0 + cur*16384;
    const u8* B1 = B0 + 8192;
    long long af[8], bfr[2];

    // ---- P0: A half0 (8 b64) + B0 j0,j1 ; stage A(t+1) ; barrier ; 16 MFMA
    #pragma unroll
    for (int i = 0; i < 8; ++i) {
      int row = wr*128 + i*16 + fr;
      af[i] = *(const long long*)(Ap + row*64 +
              ((((fk>>1) ^ ((row>>1)&3)) << 4) | ((fk&1) << 3)));
    }
    #pragma unroll
    for (int j = 0; j < 2; ++j) {
      int row = wc*64 + j*16 + fr;
      bfr[j] = *(const long long*)(B0 + row*32 +
               ((((fk>>1) ^ ((row>>2)&1)) << 4) | ((fk&1) << 3)));
    }
    stageA_f8(qa, ktn, Af0 + nxt*16384, tid);
    __builtin_amdgcn_s_barrier();
    __builtin_amdgcn_s_setprio(1);
    #pragma unroll
    for (int i = 0; i < 8; ++i) {
      acc[i][0] = MFMA8(af[i], bfr[0], acc[i][0]);
      acc[i][1] = MFMA8(af[i], bfr[1], acc[i][1]);
    }
    __builtin_amdgcn_s_setprio(0);

    // ---- P1: B0 j2,j3 ; stage B0(t+1) ; vmcnt(3) ; barrier ; 16 MFMA
    #pragma unroll
    for (int j = 0; j < 2; ++j) {
      int row = wc*64 + (2+j)*16 + fr;
      bfr[j] = *(const long long*)(B0 + row*32 +
               ((((fk>>1) ^ ((row>>2)&1)) << 4) | ((fk&1) << 3)));
    }
    stageB_f8(ka, ktn, Bf0 + nxt*16384, tid);
    asm volatile("s_waitcnt vmcnt(3)" ::: "memory");
    __builtin_amdgcn_s_barrier();
    __builtin_amdgcn_s_setprio(1);
    #pragma unroll
    for (int i = 0; i < 8; ++i) {
      acc[i][2] = MFMA8(af[i], bfr[0], acc[i][2]);
      acc[i][3] = MFMA8(af[i], bfr[1], acc[i][3]);
    }
    __builtin_amdgcn_s_setprio(0);

    // ---- P2: A half1 + B1 j0,j1 ; stage B1(t+1) ; barrier ; 16 MFMA
    #pragma unroll
    for (int i = 0; i < 8; ++i) {
      int row = wr*128 + i*16 + fr;
      af[i] = *(const long long*)(Ap + row*64 +
              (((((fk>>1)+2) ^ ((row>>1)&3)) << 4) | ((fk&1) << 3)));
    }
    #pragma unroll
    for (int j = 0; j < 2; ++j) {
      int row = wc*64 + j*16 + fr;
      bfr[j] = *(const long long*)(B1 + row*32 +
               ((((fk>>1) ^ ((row>>2)&1)) << 4) | ((fk&1) << 3)));
    }
    stageB_f8(ka, ktn + 32, Bf0 + nxt*16384 + 8192, tid);
    __builtin_amdgcn_s_barrier();
    __builtin_amdgcn_s_setprio(1);
    #pragma unroll
    for (int i = 0; i < 8; ++i) {
      acc[i][0] = MFMA8(af[i], bfr[0], acc[i][0]);
      acc[i][1] = MFMA8(af[i], bfr[1], acc[i][1]);
    }
    __builtin_amdgcn_s_setprio(0);

    // ---- P3: B1 j2,j3 ; vmcnt(1) ; barrier ; 16 MFMA
    #pragma unroll
    for (int j = 0; j < 2; ++j) {
      int row = wc*64 + (2+j)*16 + fr;
      bfr[j] = *(const long long*)(B1 + row*32 +
               ((((fk>>1) ^ ((row>>2)&1)) << 4) | ((fk&1) << 3)));
    }
    asm volatile("s_waitcnt vmcnt(1)" ::: "memory");
    __builtin_amdgcn_s_barrier();
    __builtin_amdgcn_s_setprio(1);
    #pragma unroll
    for (int i = 0; i < 8; ++i) {
      acc[i][2] = MFMA8(af[i], bfr[0], acc[i][2]);
      acc[i][3] = MFMA8(af[i], bfr[1], acc[i][3]);
    }
    __builtin_amdgcn_s_setprio(0);
  }
  // drain wrap-staged dummy DMAs, then ensure ALL waves are past GEMM LDS use
  // (and all DMA writes have landed) before the epilogue overwrites LDS.
  asm volatile("s_waitcnt vmcnt(0)" ::: "memory");
  __syncthreads();

  // ---- Epilogue: 2 passes x 64 rows; wave-private 8KB transpose tile ----------
  // Write: (rp,col_l) -> u16 idx rp*64 + ((col_l>>2 ^ rp&3)<<2 | col_l&3).
  // Read: two b64 per lane = col groups 2c2, 2c2+1 (inverse XOR); <=2-way banks.
  u16* outT = (u16*)(lds_all + w*8192);
  const float scale = 0.04419417382415922f;  // 512^-0.5
  #pragma unroll
  for (int p = 0; p < 2; ++p) {
    #pragma unroll
    for (int i2 = 0; i2 < 4; ++i2) {
      const int i = p*4 + i2;
      #pragma unroll
      for (int r = 0; r < 4; ++r) {
        int rp = i2*16 + fk*4 + r;           // row within pass [0,64)
        float s = 0.f;
        #pragma unroll
        for (int j = 0; j < 4; ++j) {
          int col_l = j*16 + fr;
          float e = __expf(acc[i][j][r] * scale);
          outT[rp*64 + ((((col_l>>2) ^ (rp&3)) << 2) | (col_l&3))] = f2bf(e);
          s += e;
        }
        s += __shfl_xor(s, 1, 64);
        s += __shfl_xor(s, 2, 64);
        s += __shfl_xor(s, 4, 64);
        s += __shfl_xor(s, 8, 64);
        if (fr == 0) atomicAdd(&ls[rowBase + wr*128 + p*64 + rp], s);
      }
    }
    asm volatile("" ::: "memory");           // fence: reads must not hoist above writes
    #pragma unroll
    for (int sb = 0; sb < 8; ++sb) {
      int rp = sb*8 + (lane >> 3);
      int c2 = lane & 7;
      int g0 = (2*c2)     ^ (rp & 3);
      int g1 = (2*c2 + 1) ^ (rp & 3);
      long long h0 = *(const long long*)(outT + rp*64 + g0*4);
      long long h1 = *(const long long*)(outT + rp*64 + g1*4);
      int nl = rowBase + wr*128 + p*64 + rp;
      int m0 = colBase + wc*64 + c2*8;
      ll2 val; val.x = h0; val.y = h1;
      *(ll2*)(Eb + (size_t)nl*4096 + m0) = val;   // 16B store, full-line coalesced
    }
    asm volatile("" ::: "memory");           // fence: pass-2 writes after pass-1 reads
  }
}

// Old 128^2 bf16 scores kernel kept for the chunked fallback path.
__global__ __launch_bounds__(256) void k_scores(const u16* __restrict__ qT,
                                                const u16* __restrict__ kT,
                                                u16* __restrict__ E,
                                                float* __restrict__ lsum,
                                                long long qkStride, long long eStride,
                                                int lsStride) {
  GEMM_PROLOGUE();
  const int bz = blockIdx.z;
  const u16* q0 = qT + (size_t)bz * qkStride;
  const u16* k0 = kT + (size_t)bz * qkStride;
  u16* Eb = E + (size_t)bz * eStride;
  float* ls = lsum + (size_t)bz * lsStride;
  const int rowBase = blockIdx.y * 128, colBase = blockIdx.x * 128;
  gemm_nt_core(q0 + (size_t)rowBase*512, 512, k0 + (size_t)colBase*512, 512,
               512, As, Bs, acc);
  const float scale = 0.04419417382415922f;
  #pragma unroll
  for (int i = 0; i < 4; ++i)
    #pragma unroll
    for (int r = 0; r < 4; ++r) {
      int nl = rowBase + wr*64 + i*16 + fk*4 + r;
      float s = 0.f;
      #pragma unroll
      for (int j = 0; j < 4; ++j) {
        int m = colBase + wc*64 + j*16 + fr;
        float e = __expf(acc[i][j][r] * scale);
        Eb[(size_t)nl*4096 + m] = f2bf(e);
        s += e;
      }
      s += __shfl_xor(s, 1, 64);
      s += __shfl_xor(s, 2, 64);
      s += __shfl_xor(s, 4, 64);
      s += __shfl_xor(s, 8, 64);
      if (fr == 0) atomicAdd(&ls[nl], s);
    }
}

// PV: out[nl][d] = (sum_m E[nl][m] * v[d][m]) / lsum[nl].
__global__ __launch_bounds__(256) void k_pv(const u16* __restrict__ E,
                                            const u16* __restrict__ vb,
                                            const float* __restrict__ lsum,
                                            u16* __restrict__ attnb,
                                            long long eStride, long long vStride,
                                            int lsStride, long long aStride,
                                            int doSwz) {
  GEMM_PROLOGUE();
  const int bz = blockIdx.z;
  const u16* Eb = E + (size_t)bz * eStride;
  const u16* vbb = vb + (size_t)bz * vStride;
  const float* ls = lsum + (size_t)bz * lsStride;
  u16* ab = attnb + (size_t)bz * aStride;
  int rowT = blockIdx.y, colT = blockIdx.x;
  if (doSwz) {             // T1: 128 blocks/slice -> 16 per XCD, grouped by E-row
    int f = blockIdx.y * 4 + blockIdx.x;
    int L = (f & 7) * 16 + (f >> 3);
    rowT = L >> 2; colT = L & 3;
  }
  const int rowBase = rowT * 128, colBase = colT * 128;
  gemm_nt_core(Eb + (size_t)rowBase*4096, 4096, vbb + (size_t)colBase*4096, 4096,
               4096, As, Bs, acc);
  #pragma unroll
  for (int i = 0; i < 4; ++i)
    #pragma unroll
    for (int r = 0; r < 4; ++r) {
      int nl = rowBase + wr*64 + i*16 + fk*4 + r;
      float rinv = 1.0f / ls[nl];
      #pragma unroll
      for (int j = 0; j < 4; ++j) {
        int d = colBase + wc*64 + j*16 + fr;
        ab[(size_t)nl*512 + d] = f2bf(acc[i][j][r] * rinv);
      }
    }
}

__global__ __launch_bounds__(256) void k_proj(const u16* __restrict__ wp,
                                              const u16* __restrict__ attn,
                                              const float* __restrict__ bproj,
                                              const float* __restrict__ x,
                                              float* __restrict__ out) {
  GEMM_PROLOGUE();
  const int bz = blockIdx.z;
  const int rowBase = blockIdx.y * 128, colBase = blockIdx.x * 128;
  gemm_nt_core(wp + (size_t)rowBase*512, 512,
               attn + ((size_t)bz*4096 + colBase)*512, 512, 512, As, Bs, acc);
  #pragma unroll
  for (int i = 0; i < 4; ++i)
    #pragma unroll
    for (int j = 0; j < 4; ++j)
      #pragma unroll
      for (int r = 0; r < 4; ++r) {
        int o = rowBase + wr*64 + i*16 + fk*4 + r;
        int n = colBase + wc*64 + j*16 + fr;
        size_t idx = ((size_t)bz*512 + o)*4096 + n;
        out[idx] = acc[i][j][r] + bproj[o] + x[idx];
      }
}

extern "C" void kernel_launch(void* const* d_in, const int* in_sizes, int n_in,
                              void* d_out, int out_size, void* d_ws, size_t ws_size,
                              hipStream_t stream) {
  const float* x      = (const float*)d_in[0];
  const float* gamma  = (const float*)d_in[1];
  const float* beta   = (const float*)d_in[2];
  const float* w_qkv  = (const float*)d_in[3];
  const float* b_qkv  = (const float*)d_in[4];
  const float* w_proj = (const float*)d_in[5];
  const float* b_proj = (const float*)d_in[6];
  float* out = (float*)d_out;
  char* ws = (char*)d_ws;

  size_t off = 0;
  u16* wqb   = (u16*)(ws + off); off += (size_t)1536*512*2;
  u16* wpb   = (u16*)(ws + off); off += (size_t)512*512*2;
  float* stats = (float*)(ws + off); off += 256;
  float* psum  = (float*)(ws + off); off += 512*4;
  float* psumsq= (float*)(ws + off); off += 512*4;
  float* lsum  = (float*)(ws + off); off += (size_t)4*4096*4;
  u16* hT    = (u16*)(ws + off);                      // reused as attn_out after QKV
  u16* attn  = hT;
  off += (size_t)4*4096*512*2;
  u16* qT    = (u16*)(ws + off); off += (size_t)4*4096*512*2;
  u16* kT    = (u16*)(ws + off); off += (size_t)4*4096*512*2;
  u16* vb    = (u16*)(ws + off); off += (size_t)4*4096*512*2;
  u16* E     = (u16*)(ws + off);
  size_t avail = ws_size > off ? ws_size - off : 0;
  const size_t fullE = (size_t)4*4096*4096*2;
  const int useF8 = (avail >= fullE) ? 1 : 0;
  // fp8 q/k reuse the bf16 q/k buffers (half the space, exclusive use per path)
  u8* qF8 = (u8*)qT;
  u8* kF8 = (u8*)kT;

  gn_stats1_k<<<512, 256, 0, stream>>>(x, psum, psumsq);
  gn_stats2_k<<<1, 32, 0, stream>>>(psum, psumsq, stats);
  gn_apply_k<<<dim3(64, 8, 4), 256, 0, stream>>>(x, gamma, beta, stats, hT);
  cast_w_k<<<3072, 256, 0, stream>>>(w_qkv, w_proj, wqb, wpb);
  k_qkv<<<dim3(12, 32, 4), 256, 0, stream>>>(hT, wqb, b_qkv, qT, kT, vb,
                                             qF8, kF8, useF8);

  if (useF8) {
    (void)hipMemsetAsync(lsum, 0, (size_t)4*4096*sizeof(float), stream);
    k_scores256_f8<<<dim3(16, 16, 4), 512, 0, stream>>>(qF8, kF8, E, lsum);
    k_pv<<<dim3(4, 32, 4), 256, 0, stream>>>(
        E, vb, lsum, attn, 4096LL*4096, 512LL*4096, 4096, 4096LL*512, 1);
  } else {
    int CH = 4096;
    while (CH > 128 && (size_t)CH*4096*2 > avail) CH >>= 1;
    for (int b = 0; b < 4; ++b) {
      for (int c0 = 0; c0 < 4096; c0 += CH) {
        (void)hipMemsetAsync(lsum, 0, (size_t)CH * sizeof(float), stream);
        k_scores<<<dim3(32, CH/128, 1), 256, 0, stream>>>(
            qT + ((size_t)b*4096 + c0)*512, kT + (size_t)b*4096*512, E, lsum, 0, 0, 0);
        k_pv<<<dim3(4, CH/128, 1), 256, 0, stream>>>(
            E, vb + (size_t)b*512*4096, lsum, attn + ((size_t)b*4096 + c0)*512, 0, 0, 0, 0, 0);
      }
    }
  }
  k_proj<<<dim3(32, 4, 4), 256, 0, stream>>>(wpb, attn, b_proj, x, out);
}

// Round 10
// 309.242 us; speedup vs baseline: 1.0582x; 1.0582x over previous
//
#include <hip/hip_runtime.h>

typedef __attribute__((ext_vector_type(8))) short bf16x8;
typedef __attribute__((ext_vector_type(4))) float f32x4;
using u16 = unsigned short;
using u8 = unsigned char;

#define DEVINL static __device__ __forceinline__

DEVINL u16 f2bf(float f) {
  union { float f; unsigned u; } v; v.f = f;
  unsigned r = v.u + 0x7FFFu + ((v.u >> 16) & 1u);   // RNE
  return (u16)(r >> 16);
}

// fp32 -> OCP e4m3fn, RNE, saturating, denormal-aware
DEVINL u8 f2e4m3(float f) {
  union { float f; unsigned u; } v; v.f = f;
  unsigned s = (v.u >> 24) & 0x80u;
  float a = fabsf(f);
  a = fminf(a, 448.f);
  union { float f; unsigned u; } b; b.f = a;
  unsigned bu = b.u + 0x7FFFFu + ((b.u >> 20) & 1u);   // RNE at bit 20
  unsigned e = bu >> 23;
  unsigned r;
  if (e >= 121) {                       // normal (>= 2^-6)
    r = ((e - 120) << 3) | ((bu >> 20) & 7u);
    if (r > 0x7Eu) r = 0x7Eu;
  } else {                              // denormal: round(a * 512)
    r = (unsigned)(a * 512.f + 0.5f);
    if (r > 7u) r = 8u;                 // bumps to min normal
  }
  return (u8)(r | s);
}

DEVINL void gload16(const u16* g, u16* l) {
  __builtin_amdgcn_global_load_lds((const __attribute__((address_space(1))) void*)g,
                                   (__attribute__((address_space(3))) void*)l,
                                   16, 0, 0);
}
DEVINL void gload16b(const u8* g, u8* l) {
  __builtin_amdgcn_global_load_lds((const __attribute__((address_space(1))) void*)g,
                                   (__attribute__((address_space(3))) void*)l,
                                   16, 0, 0);
}

// ---------------- GroupNorm stats: two-stage, 512-block parallel ----------------
__global__ __launch_bounds__(256) void gn_stats1_k(const float* __restrict__ x,
                                                   float* __restrict__ psum,
                                                   float* __restrict__ psumsq) {
  const int blk = blockIdx.x;
  const float4* p4 = (const float4*)(x + (size_t)(blk >> 4) * (64 * 4096))
                     + (size_t)(blk & 15) * 4096;
  float s = 0.f, ss = 0.f;
  #pragma unroll
  for (int i = 0; i < 16; ++i) {
    float4 v = p4[i*256 + threadIdx.x];
    s  += v.x + v.y + v.z + v.w;
    ss += v.x*v.x + v.y*v.y + v.z*v.z + v.w*v.w;
  }
  #pragma unroll
  for (int off = 32; off > 0; off >>= 1) {
    s  += __shfl_down(s, off, 64);
    ss += __shfl_down(ss, off, 64);
  }
  __shared__ float rs[4], rss[4];
  const int lane = threadIdx.x & 63, w = threadIdx.x >> 6;
  if (lane == 0) { rs[w] = s; rss[w] = ss; }
  __syncthreads();
  if (threadIdx.x == 0) {
    psum[blk]   = rs[0]+rs[1]+rs[2]+rs[3];
    psumsq[blk] = rss[0]+rss[1]+rss[2]+rss[3];
  }
}

__global__ void gn_stats2_k(const float* __restrict__ psum,
                            const float* __restrict__ psumsq,
                            float* __restrict__ stats) {
  const int bg = threadIdx.x;   // 32 threads
  if (bg >= 32) return;
  float s = 0.f, ss = 0.f;
  #pragma unroll
  for (int p = 0; p < 16; ++p) { s += psum[bg*16+p]; ss += psumsq[bg*16+p]; }
  const float inv = 1.f / 262144.f;
  float mean = s * inv;
  float var  = ss * inv - mean * mean;
  stats[bg*2]   = mean;
  stats[bg*2+1] = rsqrtf(var + 1e-5f);
}

// Normalize + transpose: x[b][c][n] -> hT[b][n][c] bf16.
__global__ __launch_bounds__(256) void gn_apply_k(const float* __restrict__ x,
                                                  const float* __restrict__ gamma,
                                                  const float* __restrict__ beta,
                                                  const float* __restrict__ stats,
                                                  u16* __restrict__ hT) {
  __shared__ u16 tile[64][65];
  const int b = blockIdx.z, ct = blockIdx.y, nt = blockIdx.x;
  const int t = threadIdx.x;
  const float mean = stats[(b*8 + ct)*2 + 0];
  const float rstd = stats[(b*8 + ct)*2 + 1];
  const float* xb = x + ((size_t)b*512 + (size_t)ct*64) * 4096 + nt*64;
  #pragma unroll
  for (int i = 0; i < 16; ++i) {
    int idx = i*256 + t; int cl = idx >> 6, nl = idx & 63;
    float v  = xb[(size_t)cl*4096 + nl];
    float hn = (v - mean) * rstd * gamma[ct*64 + cl] + beta[ct*64 + cl];
    tile[cl][nl] = f2bf(hn);
  }
  __syncthreads();
  u16* o = hT + ((size_t)b*4096 + (size_t)nt*64) * 512 + ct*64;
  #pragma unroll
  for (int i = 0; i < 16; ++i) {
    int idx = i*256 + t; int nl = idx >> 6, cl = idx & 63;
    o[(size_t)nl*512 + cl] = tile[cl][nl];
  }
}

__global__ __launch_bounds__(256) void cast_w_k(const float* __restrict__ wq,
                                                const float* __restrict__ wp,
                                                u16* __restrict__ wqb,
                                                u16* __restrict__ wpb) {
  int i = blockIdx.x*256 + threadIdx.x;
  if (i < 1536*512) wqb[i] = f2bf(wq[i]);
  if (i < 512*512)  wpb[i] = f2bf(wp[i]);
}

// ---------------- NT GEMM core (m97 structure, 128x128, 4 waves) ----------------
DEVINL void gemm_nt_core(const u16* __restrict__ A, int lda,
                         const u16* __restrict__ B, int ldb,
                         int K, u16* As, u16* Bs, f32x4 acc[4][4]) {
  const int tid = threadIdx.x;
  const int lane = tid & 63, w = tid >> 6;
  const int wr = w >> 1, wc = w & 1;
  const int fr = lane & 15, fk = lane >> 4;
  for (int kt = 0; kt < K; kt += 64) {
    #pragma unroll
    for (int i = 0; i < 4; ++i) {
      int ch = i*256 + tid;
      int row = ch >> 3, kc = ch & 7;
      gload16(A + (size_t)row*lda + kt + kc*8, As + ch*8);
      gload16(B + (size_t)row*ldb + kt + kc*8, Bs + ch*8);
    }
    __syncthreads();
    #pragma unroll
    for (int kk = 0; kk < 2; ++kk) {
      bf16x8 af[4], bfg[4];
      #pragma unroll
      for (int i = 0; i < 4; ++i)
        af[i] = *(const bf16x8*)(As + ((wr*64 + i*16 + fr)*64 + kk*32 + fk*8));
      #pragma unroll
      for (int j = 0; j < 4; ++j)
        bfg[j] = *(const bf16x8*)(Bs + ((wc*64 + j*16 + fr)*64 + kk*32 + fk*8));
      #pragma unroll
      for (int i = 0; i < 4; ++i)
        #pragma unroll
        for (int j = 0; j < 4; ++j)
          acc[i][j] = __builtin_amdgcn_mfma_f32_16x16x32_bf16(af[i], bfg[j], acc[i][j], 0, 0, 0);
    }
    __syncthreads();
  }
}

#define GEMM_PROLOGUE() \
  __shared__ __align__(16) u16 As[128*64]; \
  __shared__ __align__(16) u16 Bs[128*64]; \
  f32x4 acc[4][4] = {}; \
  const int tid = threadIdx.x; \
  const int lane = tid & 63, w = tid >> 6; \
  const int wr = w >> 1, wc = w & 1; \
  const int fr = lane & 15, fk = lane >> 4; \
  (void)lane;

// QKV. useF8: q,k stored as fp8 e4m3 (for the fp8 scores path); else bf16.
__global__ __launch_bounds__(256) void k_qkv(const u16* __restrict__ hT,
                                             const u16* __restrict__ wq,
                                             const float* __restrict__ bqkv,
                                             u16* __restrict__ qT, u16* __restrict__ kT,
                                             u16* __restrict__ vb,
                                             u8* __restrict__ qF8, u8* __restrict__ kF8,
                                             int useF8) {
  GEMM_PROLOGUE();
  const int bz = blockIdx.z;
  const int rowBase = blockIdx.y * 128, colBase = blockIdx.x * 128;
  gemm_nt_core(hT + ((size_t)bz*4096 + rowBase)*512, 512,
               wq + (size_t)colBase*512, 512, 512, As, Bs, acc);
  #pragma unroll
  for (int i = 0; i < 4; ++i)
    #pragma unroll
    for (int j = 0; j < 4; ++j)
      #pragma unroll
      for (int r = 0; r < 4; ++r) {
        int n = rowBase + wr*64 + i*16 + fk*4 + r;
        int o = colBase + wc*64 + j*16 + fr;
        float val = acc[i][j][r] + bqkv[o];
        if (useF8) {
          if (o < 512)       qF8[((size_t)bz*4096 + n)*512 + o]         = f2e4m3(val);
          else if (o < 1024) kF8[((size_t)bz*4096 + n)*512 + (o - 512)] = f2e4m3(val);
          else               vb[((size_t)bz*512 + (o - 1024))*4096 + n] = f2bf(val);
        } else {
          u16 u = f2bf(val);
          if (o < 512)       qT[((size_t)bz*4096 + n)*512 + o]          = u;
          else if (o < 1024) kT[((size_t)bz*4096 + n)*512 + (o - 512)]  = u;
          else               vb[((size_t)bz*512 + (o - 1024))*4096 + n] = u;
        }
      }
}

// ------------- Scores (fp8): 128x128 tile, m97 2-barrier core, 4 waves ----------
// ~4 blocks/CU co-resident (16 KB LDS, ~110 VGPR) -> cross-block overlap hides
// barrier drains (m97/m114 mechanism). Both LDS planes [128 rows][64 B] with
// 16B-slot XOR swizzle slot^=(row>>1)&3 (verified 0-conflict in r6/r7 A-plane);
// inverse swizzle on the global source (rule #21).
#define MFMA8(a, b, c) __builtin_amdgcn_mfma_f32_16x16x32_fp8_fp8((a), (b), (c), 0, 0, 0)

__global__ __launch_bounds__(256) void k_scores128_f8(const u8* __restrict__ qF8,
                                                      const u8* __restrict__ kF8,
                                                      u16* __restrict__ E,
                                                      float* __restrict__ lsum) {
  __shared__ __align__(16) u8 Af[128*64];   // 8 KB
  __shared__ __align__(16) u8 Bf[128*64];   // 8 KB
  f32x4 acc[4][4] = {};
  const int tid = threadIdx.x;
  const int lane = tid & 63, w = tid >> 6;
  const int wr = w >> 1, wc = w & 1;
  const int fr = lane & 15, fk = lane >> 4;
  const int bz = blockIdx.z;
  // T1: bijective XCD swizzle, 1024 blocks/slice (1024%8==0). Per XCD:
  // 4 Q-row panels x all K = 2.25 MB fp8 -> fits 4 MB L2.
  int f = blockIdx.y * 32 + blockIdx.x;
  int L = (f & 7) * 128 + (f >> 3);
  const int rowBase = (L >> 5) * 128, colBase = (L & 31) * 128;
  const u8* qa = qF8 + (size_t)bz*4096*512 + (size_t)rowBase*512;
  const u8* ka = kF8 + (size_t)bz*4096*512 + (size_t)colBase*512;
  u16* Eb = E + (size_t)bz*4096*4096;
  float* ls = lsum + (size_t)bz*4096;

  for (int kt = 0; kt < 512; kt += 64) {
    #pragma unroll
    for (int q = 0; q < 2; ++q) {
      int c = q*256 + tid;                  // 512 chunks of 16B per plane
      int row = c >> 2, s16 = c & 3;
      int kc = s16 ^ ((row >> 1) & 3);      // inverse swizzle on global source
      gload16b(qa + (size_t)row*512 + kt + kc*16, Af + c*16);
      gload16b(ka + (size_t)row*512 + kt + kc*16, Bf + c*16);
    }
    __syncthreads();                        // compiler drains vmcnt before barrier
    #pragma unroll
    for (int kk = 0; kk < 2; ++kk) {
      long long a8[4], b8[4];
      #pragma unroll
      for (int i = 0; i < 4; ++i) {
        int row = wr*64 + i*16 + fr;
        a8[i] = *(const long long*)(Af + row*64 +
                ((((kk*2 + (fk>>1)) ^ ((row>>1)&3)) << 4) | ((fk&1) << 3)));
      }
      #pragma unroll
      for (int j = 0; j < 4; ++j) {
        int row = wc*64 + j*16 + fr;
        b8[j] = *(const long long*)(Bf + row*64 +
                ((((kk*2 + (fk>>1)) ^ ((row>>1)&3)) << 4) | ((fk&1) << 3)));
      }
      #pragma unroll
      for (int i = 0; i < 4; ++i)
        #pragma unroll
        for (int j = 0; j < 4; ++j)
          acc[i][j] = MFMA8(a8[i], b8[j], acc[i][j]);
    }
    __syncthreads();
  }

  const float scale = 0.04419417382415922f;  // 512^-0.5
  #pragma unroll
  for (int i = 0; i < 4; ++i)
    #pragma unroll
    for (int r = 0; r < 4; ++r) {
      int nl = rowBase + wr*64 + i*16 + fk*4 + r;
      float s = 0.f;
      #pragma unroll
      for (int j = 0; j < 4; ++j) {
        int m = colBase + wc*64 + j*16 + fr;
        float e = __expf(acc[i][j][r] * scale);
        Eb[(size_t)nl*4096 + m] = f2bf(e);
        s += e;
      }
      s += __shfl_xor(s, 1, 64);
      s += __shfl_xor(s, 2, 64);
      s += __shfl_xor(s, 4, 64);
      s += __shfl_xor(s, 8, 64);
      if (fr == 0) atomicAdd(&ls[nl], s);
    }
}

// Old 128^2 bf16 scores kernel kept for the chunked fallback path.
__global__ __launch_bounds__(256) void k_scores(const u16* __restrict__ qT,
                                                const u16* __restrict__ kT,
                                                u16* __restrict__ E,
                                                float* __restrict__ lsum,
                                                long long qkStride, long long eStride,
                                                int lsStride) {
  GEMM_PROLOGUE();
  const int bz = blockIdx.z;
  const u16* q0 = qT + (size_t)bz * qkStride;
  const u16* k0 = kT + (size_t)bz * qkStride;
  u16* Eb = E + (size_t)bz * eStride;
  float* ls = lsum + (size_t)bz * lsStride;
  const int rowBase = blockIdx.y * 128, colBase = blockIdx.x * 128;
  gemm_nt_core(q0 + (size_t)rowBase*512, 512, k0 + (size_t)colBase*512, 512,
               512, As, Bs, acc);
  const float scale = 0.04419417382415922f;
  #pragma unroll
  for (int i = 0; i < 4; ++i)
    #pragma unroll
    for (int r = 0; r < 4; ++r) {
      int nl = rowBase + wr*64 + i*16 + fk*4 + r;
      float s = 0.f;
      #pragma unroll
      for (int j = 0; j < 4; ++j) {
        int m = colBase + wc*64 + j*16 + fr;
        float e = __expf(acc[i][j][r] * scale);
        Eb[(size_t)nl*4096 + m] = f2bf(e);
        s += e;
      }
      s += __shfl_xor(s, 1, 64);
      s += __shfl_xor(s, 2, 64);
      s += __shfl_xor(s, 4, 64);
      s += __shfl_xor(s, 8, 64);
      if (fr == 0) atomicAdd(&ls[nl], s);
    }
}

// PV: out[nl][d] = (sum_m E[nl][m] * v[d][m]) / lsum[nl].
__global__ __launch_bounds__(256) void k_pv(const u16* __restrict__ E,
                                            const u16* __restrict__ vb,
                                            const float* __restrict__ lsum,
                                            u16* __restrict__ attnb,
                                            long long eStride, long long vStride,
                                            int lsStride, long long aStride,
                                            int doSwz) {
  GEMM_PROLOGUE();
  const int bz = blockIdx.z;
  const u16* Eb = E + (size_t)bz * eStride;
  const u16* vbb = vb + (size_t)bz * vStride;
  const float* ls = lsum + (size_t)bz * lsStride;
  u16* ab = attnb + (size_t)bz * aStride;
  int rowT = blockIdx.y, colT = blockIdx.x;
  if (doSwz) {             // T1: 128 blocks/slice -> 16 per XCD, grouped by E-row
    int f = blockIdx.y * 4 + blockIdx.x;
    int L = (f & 7) * 16 + (f >> 3);
    rowT = L >> 2; colT = L & 3;
  }
  const int rowBase = rowT * 128, colBase = colT * 128;
  gemm_nt_core(Eb + (size_t)rowBase*4096, 4096, vbb + (size_t)colBase*4096, 4096,
               4096, As, Bs, acc);
  #pragma unroll
  for (int i = 0; i < 4; ++i)
    #pragma unroll
    for (int r = 0; r < 4; ++r) {
      int nl = rowBase + wr*64 + i*16 + fk*4 + r;
      float rinv = 1.0f / ls[nl];
      #pragma unroll
      for (int j = 0; j < 4; ++j) {
        int d = colBase + wc*64 + j*16 + fr;
        ab[(size_t)nl*512 + d] = f2bf(acc[i][j][r] * rinv);
      }
    }
}

__global__ __launch_bounds__(256) void k_proj(const u16* __restrict__ wp,
                                              const u16* __restrict__ attn,
                                              const float* __restrict__ bproj,
                                              const float* __restrict__ x,
                                              float* __restrict__ out) {
  GEMM_PROLOGUE();
  const int bz = blockIdx.z;
  const int rowBase = blockIdx.y * 128, colBase = blockIdx.x * 128;
  gemm_nt_core(wp + (size_t)rowBase*512, 512,
               attn + ((size_t)bz*4096 + colBase)*512, 512, 512, As, Bs, acc);
  #pragma unroll
  for (int i = 0; i < 4; ++i)
    #pragma unroll
    for (int j = 0; j < 4; ++j)
      #pragma unroll
      for (int r = 0; r < 4; ++r) {
        int o = rowBase + wr*64 + i*16 + fk*4 + r;
        int n = colBase + wc*64 + j*16 + fr;
        size_t idx = ((size_t)bz*512 + o)*4096 + n;
        out[idx] = acc[i][j][r] + bproj[o] + x[idx];
      }
}

extern "C" void kernel_launch(void* const* d_in, const int* in_sizes, int n_in,
                              void* d_out, int out_size, void* d_ws, size_t ws_size,
                              hipStream_t stream) {
  const float* x      = (const float*)d_in[0];
  const float* gamma  = (const float*)d_in[1];
  const float* beta   = (const float*)d_in[2];
  const float* w_qkv  = (const float*)d_in[3];
  const float* b_qkv  = (const float*)d_in[4];
  const float* w_proj = (const float*)d_in[5];
  const float* b_proj = (const float*)d_in[6];
  float* out = (float*)d_out;
  char* ws = (char*)d_ws;

  size_t off = 0;
  u16* wqb   = (u16*)(ws + off); off += (size_t)1536*512*2;
  u16* wpb   = (u16*)(ws + off); off += (size_t)512*512*2;
  float* stats = (float*)(ws + off); off += 256;
  float* psum  = (float*)(ws + off); off += 512*4;
  float* psumsq= (float*)(ws + off); off += 512*4;
  float* lsum  = (float*)(ws + off); off += (size_t)4*4096*4;
  u16* hT    = (u16*)(ws + off);                      // reused as attn_out after QKV
  u16* attn  = hT;
  off += (size_t)4*4096*512*2;
  u16* qT    = (u16*)(ws + off); off += (size_t)4*4096*512*2;
  u16* kT    = (u16*)(ws + off); off += (size_t)4*4096*512*2;
  u16* vb    = (u16*)(ws + off); off += (size_t)4*4096*512*2;
  u16* E     = (u16*)(ws + off);
  size_t avail = ws_size > off ? ws_size - off : 0;
  const size_t fullE = (size_t)4*4096*4096*2;
  const int useF8 = (avail >= fullE) ? 1 : 0;
  // fp8 q/k reuse the bf16 q/k buffers (half the space, exclusive use per path)
  u8* qF8 = (u8*)qT;
  u8* kF8 = (u8*)kT;

  gn_stats1_k<<<512, 256, 0, stream>>>(x, psum, psumsq);
  gn_stats2_k<<<1, 32, 0, stream>>>(psum, psumsq, stats);
  gn_apply_k<<<dim3(64, 8, 4), 256, 0, stream>>>(x, gamma, beta, stats, hT);
  cast_w_k<<<3072, 256, 0, stream>>>(w_qkv, w_proj, wqb, wpb);
  k_qkv<<<dim3(12, 32, 4), 256, 0, stream>>>(hT, wqb, b_qkv, qT, kT, vb,
                                             qF8, kF8, useF8);

  if (useF8) {
    (void)hipMemsetAsync(lsum, 0, (size_t)4*4096*sizeof(float), stream);
    k_scores128_f8<<<dim3(32, 32, 4), 256, 0, stream>>>(qF8, kF8, E, lsum);
    k_pv<<<dim3(4, 32, 4), 256, 0, stream>>>(
        E, vb, lsum, attn, 4096LL*4096, 512LL*4096, 4096, 4096LL*512, 1);
  } else {
    int CH = 4096;
    while (CH > 128 && (size_t)CH*4096*2 > avail) CH >>= 1;
    for (int b = 0; b < 4; ++b) {
      for (int c0 = 0; c0 < 4096; c0 += CH) {
        (void)hipMemsetAsync(lsum, 0, (size_t)CH * sizeof(float), stream);
        k_scores<<<dim3(32, CH/128, 1), 256, 0, stream>>>(
            qT + ((size_t)b*4096 + c0)*512, kT + (size_t)b*4096*512, E, lsum, 0, 0, 0);
        k_pv<<<dim3(4, CH/128, 1), 256, 0, stream>>>(
            E, vb + (size_t)b*512*4096, lsum, attn + ((size_t)b*4096 + c0)*512, 0, 0, 0, 0, 0);
      }
    }
  }
  k_proj<<<dim3(32, 4, 4), 256, 0, stream>>>(wpb, attn, b_proj, x, out);
}

// Round 11
// 301.389 us; speedup vs baseline: 1.0858x; 1.0261x over previous
//
#include <hip/hip_runtime.h>

typedef __attribute__((ext_vector_type(8))) short bf16x8;
typedef __attribute__((ext_vector_type(4))) float f32x4;
using u16 = unsigned short;
using u8 = unsigned char;

#define DEVINL static __device__ __forceinline__

DEVINL u16 f2bf(float f) {
  union { float f; unsigned u; } v; v.f = f;
  unsigned r = v.u + 0x7FFFu + ((v.u >> 16) & 1u);   // RNE
  return (u16)(r >> 16);
}

// fp32 -> OCP e4m3fn, RNE, saturating, denormal-aware
DEVINL u8 f2e4m3(float f) {
  union { float f; unsigned u; } v; v.f = f;
  unsigned s = (v.u >> 24) & 0x80u;
  float a = fabsf(f);
  a = fminf(a, 448.f);
  union { float f; unsigned u; } b; b.f = a;
  unsigned bu = b.u + 0x7FFFFu + ((b.u >> 20) & 1u);   // RNE at bit 20
  unsigned e = bu >> 23;
  unsigned r;
  if (e >= 121) {                       // normal (>= 2^-6)
    r = ((e - 120) << 3) | ((bu >> 20) & 7u);
    if (r > 0x7Eu) r = 0x7Eu;
  } else {                              // denormal: round(a * 512)
    r = (unsigned)(a * 512.f + 0.5f);
    if (r > 7u) r = 8u;                 // bumps to min normal
  }
  return (u8)(r | s);
}

DEVINL void gload16(const u16* g, u16* l) {
  __builtin_amdgcn_global_load_lds((const __attribute__((address_space(1))) void*)g,
                                   (__attribute__((address_space(3))) void*)l,
                                   16, 0, 0);
}
DEVINL void gload16b(const u8* g, u8* l) {
  __builtin_amdgcn_global_load_lds((const __attribute__((address_space(1))) void*)g,
                                   (__attribute__((address_space(3))) void*)l,
                                   16, 0, 0);
}

// ---------------- GroupNorm stats: two-stage, 512-block parallel ----------------
__global__ __launch_bounds__(256) void gn_stats1_k(const float* __restrict__ x,
                                                   float* __restrict__ psum,
                                                   float* __restrict__ psumsq) {
  const int blk = blockIdx.x;
  const float4* p4 = (const float4*)(x + (size_t)(blk >> 4) * (64 * 4096))
                     + (size_t)(blk & 15) * 4096;
  float s = 0.f, ss = 0.f;
  #pragma unroll
  for (int i = 0; i < 16; ++i) {
    float4 v = p4[i*256 + threadIdx.x];
    s  += v.x + v.y + v.z + v.w;
    ss += v.x*v.x + v.y*v.y + v.z*v.z + v.w*v.w;
  }
  #pragma unroll
  for (int off = 32; off > 0; off >>= 1) {
    s  += __shfl_down(s, off, 64);
    ss += __shfl_down(ss, off, 64);
  }
  __shared__ float rs[4], rss[4];
  const int lane = threadIdx.x & 63, w = threadIdx.x >> 6;
  if (lane == 0) { rs[w] = s; rss[w] = ss; }
  __syncthreads();
  if (threadIdx.x == 0) {
    psum[blk]   = rs[0]+rs[1]+rs[2]+rs[3];
    psumsq[blk] = rss[0]+rss[1]+rss[2]+rss[3];
  }
}

__global__ void gn_stats2_k(const float* __restrict__ psum,
                            const float* __restrict__ psumsq,
                            float* __restrict__ stats) {
  const int bg = threadIdx.x;   // 32 threads
  if (bg >= 32) return;
  float s = 0.f, ss = 0.f;
  #pragma unroll
  for (int p = 0; p < 16; ++p) { s += psum[bg*16+p]; ss += psumsq[bg*16+p]; }
  const float inv = 1.f / 262144.f;
  float mean = s * inv;
  float var  = ss * inv - mean * mean;
  stats[bg*2]   = mean;
  stats[bg*2+1] = rsqrtf(var + 1e-5f);
}

// Normalize + transpose: x[b][c][n] -> hT[b][n][c] bf16.
__global__ __launch_bounds__(256) void gn_apply_k(const float* __restrict__ x,
                                                  const float* __restrict__ gamma,
                                                  const float* __restrict__ beta,
                                                  const float* __restrict__ stats,
                                                  u16* __restrict__ hT) {
  __shared__ u16 tile[64][65];
  const int b = blockIdx.z, ct = blockIdx.y, nt = blockIdx.x;
  const int t = threadIdx.x;
  const float mean = stats[(b*8 + ct)*2 + 0];
  const float rstd = stats[(b*8 + ct)*2 + 1];
  const float* xb = x + ((size_t)b*512 + (size_t)ct*64) * 4096 + nt*64;
  #pragma unroll
  for (int i = 0; i < 16; ++i) {
    int idx = i*256 + t; int cl = idx >> 6, nl = idx & 63;
    float v  = xb[(size_t)cl*4096 + nl];
    float hn = (v - mean) * rstd * gamma[ct*64 + cl] + beta[ct*64 + cl];
    tile[cl][nl] = f2bf(hn);
  }
  __syncthreads();
  u16* o = hT + ((size_t)b*4096 + (size_t)nt*64) * 512 + ct*64;
  #pragma unroll
  for (int i = 0; i < 16; ++i) {
    int idx = i*256 + t; int nl = idx >> 6, cl = idx & 63;
    o[(size_t)nl*512 + cl] = tile[cl][nl];
  }
}

__global__ __launch_bounds__(256) void cast_w_k(const float* __restrict__ wq,
                                                const float* __restrict__ wp,
                                                u16* __restrict__ wqb,
                                                u16* __restrict__ wpb) {
  int i = blockIdx.x*256 + threadIdx.x;
  if (i < 1536*512) wqb[i] = f2bf(wq[i]);
  if (i < 512*512)  wpb[i] = f2bf(wp[i]);
}

// ---------------- NT GEMM core (m97 structure, 128x128, 4 waves, bf16) ----------
DEVINL void gemm_nt_core(const u16* __restrict__ A, int lda,
                         const u16* __restrict__ B, int ldb,
                         int K, u16* As, u16* Bs, f32x4 acc[4][4]) {
  const int tid = threadIdx.x;
  const int lane = tid & 63, w = tid >> 6;
  const int wr = w >> 1, wc = w & 1;
  const int fr = lane & 15, fk = lane >> 4;
  for (int kt = 0; kt < K; kt += 64) {
    #pragma unroll
    for (int i = 0; i < 4; ++i) {
      int ch = i*256 + tid;
      int row = ch >> 3, kc = ch & 7;
      gload16(A + (size_t)row*lda + kt + kc*8, As + ch*8);
      gload16(B + (size_t)row*ldb + kt + kc*8, Bs + ch*8);
    }
    __syncthreads();
    #pragma unroll
    for (int kk = 0; kk < 2; ++kk) {
      bf16x8 af[4], bfg[4];
      #pragma unroll
      for (int i = 0; i < 4; ++i)
        af[i] = *(const bf16x8*)(As + ((wr*64 + i*16 + fr)*64 + kk*32 + fk*8));
      #pragma unroll
      for (int j = 0; j < 4; ++j)
        bfg[j] = *(const bf16x8*)(Bs + ((wc*64 + j*16 + fr)*64 + kk*32 + fk*8));
      #pragma unroll
      for (int i = 0; i < 4; ++i)
        #pragma unroll
        for (int j = 0; j < 4; ++j)
          acc[i][j] = __builtin_amdgcn_mfma_f32_16x16x32_bf16(af[i], bfg[j], acc[i][j], 0, 0, 0);
    }
    __syncthreads();
  }
}

#define GEMM_PROLOGUE() \
  __shared__ __align__(16) u16 As[128*64]; \
  __shared__ __align__(16) u16 Bs[128*64]; \
  f32x4 acc[4][4] = {}; \
  const int tid = threadIdx.x; \
  const int lane = tid & 63, w = tid >> 6; \
  const int wr = w >> 1, wc = w & 1; \
  const int fr = lane & 15, fk = lane >> 4; \
  (void)lane;

// ---------------- NT GEMM core (fp8 e4m3, 128x128 tile, BK=128, 4 waves) --------
// LDS planes [128 rows][128 B]; 16B-slot swizzle: s16 ^= (row>>1)&7 (period 16,
// residual 2-way = free). Inverse swizzle on the global source (rule #21).
// Fragment path (row, k=kk*32+fk*8) HW-verified in round 10.
#define MFMA8(a, b, c) __builtin_amdgcn_mfma_f32_16x16x32_fp8_fp8((a), (b), (c), 0, 0, 0)

DEVINL void gemm_nt_f8(const u8* __restrict__ A, int lda,
                       const u8* __restrict__ B, int ldb,
                       int K, u8* Af, u8* Bf, f32x4 acc[4][4]) {
  const int tid = threadIdx.x;
  const int lane = tid & 63, w = tid >> 6;
  const int wr = w >> 1, wc = w & 1;
  const int fr = lane & 15, fk = lane >> 4;
  for (int kt = 0; kt < K; kt += 128) {
    #pragma unroll
    for (int q = 0; q < 4; ++q) {
      int c = q*256 + tid;                  // 1024 chunks of 16B per plane
      int row = c >> 3, s16 = c & 7;
      int kc = s16 ^ ((row >> 1) & 7);      // inverse swizzle on global source
      gload16b(A + (size_t)row*lda + kt + kc*16, Af + c*16);
      gload16b(B + (size_t)row*ldb + kt + kc*16, Bf + c*16);
    }
    __syncthreads();                        // compiler drains vmcnt before barrier
    #pragma unroll
    for (int kk = 0; kk < 4; ++kk) {
      long long a8[4], b8[4];
      #pragma unroll
      for (int i = 0; i < 4; ++i) {
        int row = wr*64 + i*16 + fr;
        int s16r = (kk*2 + (fk>>1)) ^ ((row>>1)&7);
        a8[i] = *(const long long*)(Af + row*128 + (s16r<<4) + ((fk&1)<<3));
      }
      #pragma unroll
      for (int j = 0; j < 4; ++j) {
        int row = wc*64 + j*16 + fr;
        int s16r = (kk*2 + (fk>>1)) ^ ((row>>1)&7);
        b8[j] = *(const long long*)(Bf + row*128 + (s16r<<4) + ((fk&1)<<3));
      }
      #pragma unroll
      for (int i = 0; i < 4; ++i)
        #pragma unroll
        for (int j = 0; j < 4; ++j)
          acc[i][j] = MFMA8(a8[i], b8[j], acc[i][j]);
    }
    __syncthreads();
  }
}

// QKV. useF8: q,k,v stored as fp8 e4m3 (fp8 attention path); else bf16.
__global__ __launch_bounds__(256) void k_qkv(const u16* __restrict__ hT,
                                             const u16* __restrict__ wq,
                                             const float* __restrict__ bqkv,
                                             u16* __restrict__ qT, u16* __restrict__ kT,
                                             u16* __restrict__ vb,
                                             u8* __restrict__ qF8, u8* __restrict__ kF8,
                                             u8* __restrict__ vF8, int useF8) {
  GEMM_PROLOGUE();
  const int bz = blockIdx.z;
  const int rowBase = blockIdx.y * 128, colBase = blockIdx.x * 128;
  gemm_nt_core(hT + ((size_t)bz*4096 + rowBase)*512, 512,
               wq + (size_t)colBase*512, 512, 512, As, Bs, acc);
  #pragma unroll
  for (int i = 0; i < 4; ++i)
    #pragma unroll
    for (int j = 0; j < 4; ++j)
      #pragma unroll
      for (int r = 0; r < 4; ++r) {
        int n = rowBase + wr*64 + i*16 + fk*4 + r;
        int o = colBase + wc*64 + j*16 + fr;
        float val = acc[i][j][r] + bqkv[o];
        if (useF8) {
          if (o < 512)       qF8[((size_t)bz*4096 + n)*512 + o]         = f2e4m3(val);
          else if (o < 1024) kF8[((size_t)bz*4096 + n)*512 + (o - 512)] = f2e4m3(val);
          else               vF8[((size_t)bz*512 + (o - 1024))*4096 + n] = f2e4m3(val);
        } else {
          u16 u = f2bf(val);
          if (o < 512)       qT[((size_t)bz*4096 + n)*512 + o]          = u;
          else if (o < 1024) kT[((size_t)bz*4096 + n)*512 + (o - 512)]  = u;
          else               vb[((size_t)bz*512 + (o - 1024))*4096 + n] = u;
        }
      }
}

// ------------- Scores (fp8): 128x128 tile, BK=128, E stored fp8 -----------------
__global__ __launch_bounds__(256) void k_scores128_f8(const u8* __restrict__ qF8,
                                                      const u8* __restrict__ kF8,
                                                      u8* __restrict__ E8,
                                                      float* __restrict__ lsum) {
  __shared__ __align__(16) u8 Af[128*128];   // 16 KB
  __shared__ __align__(16) u8 Bf[128*128];   // 16 KB
  f32x4 acc[4][4] = {};
  const int tid = threadIdx.x;
  const int lane = tid & 63, w = tid >> 6;
  const int wr = w >> 1, wc = w & 1;
  const int fr = lane & 15, fk = lane >> 4;
  const int bz = blockIdx.z;
  // T1: bijective XCD swizzle, 1024 blocks/slice (1024%8==0).
  int f = blockIdx.y * 32 + blockIdx.x;
  int L = (f & 7) * 128 + (f >> 3);
  const int rowBase = (L >> 5) * 128, colBase = (L & 31) * 128;
  const u8* qa = qF8 + (size_t)bz*4096*512 + (size_t)rowBase*512;
  const u8* ka = kF8 + (size_t)bz*4096*512 + (size_t)colBase*512;
  u8* Eb = E8 + (size_t)bz*4096*4096;
  float* ls = lsum + (size_t)bz*4096;

  gemm_nt_f8(qa, 512, ka, 512, 512, Af, Bf, acc);

  const float scale = 0.04419417382415922f;  // 512^-0.5
  #pragma unroll
  for (int i = 0; i < 4; ++i)
    #pragma unroll
    for (int r = 0; r < 4; ++r) {
      int nl = rowBase + wr*64 + i*16 + fk*4 + r;
      float s = 0.f;
      #pragma unroll
      for (int j = 0; j < 4; ++j) {
        int m = colBase + wc*64 + j*16 + fr;
        float e = __expf(acc[i][j][r] * scale);
        Eb[(size_t)nl*4096 + m] = f2e4m3(e);
        s += e;
      }
      s += __shfl_xor(s, 1, 64);
      s += __shfl_xor(s, 2, 64);
      s += __shfl_xor(s, 4, 64);
      s += __shfl_xor(s, 8, 64);
      if (fr == 0) atomicAdd(&ls[nl], s);
    }
}

// ------------- PV (fp8): out[nl][d] = (sum_m E[nl][m] * v[d][m]) / lsum[nl] -----
__global__ __launch_bounds__(256) void k_pv_f8(const u8* __restrict__ E8,
                                               const u8* __restrict__ vF8,
                                               const float* __restrict__ lsum,
                                               u16* __restrict__ attnb) {
  __shared__ __align__(16) u8 Af[128*128];   // 16 KB
  __shared__ __align__(16) u8 Bf[128*128];   // 16 KB
  f32x4 acc[4][4] = {};
  const int tid = threadIdx.x;
  const int lane = tid & 63, w = tid >> 6;
  const int wr = w >> 1, wc = w & 1;
  const int fr = lane & 15, fk = lane >> 4;
  const int bz = blockIdx.z;
  // T1: bijective XCD swizzle, 128 blocks/slice (128%8==0), grouped by E-row.
  int f = blockIdx.y * 4 + blockIdx.x;
  int L = (f & 7) * 16 + (f >> 3);
  const int rowBase = (L >> 2) * 128, colBase = (L & 3) * 128;
  const u8* Eb = E8 + (size_t)bz*4096*4096 + (size_t)rowBase*4096;
  const u8* vbb = vF8 + (size_t)bz*512*4096 + (size_t)colBase*4096;
  const float* ls = lsum + (size_t)bz*4096;
  u16* ab = attnb + (size_t)bz*4096*512;

  gemm_nt_f8(Eb, 4096, vbb, 4096, 4096, Af, Bf, acc);

  #pragma unroll
  for (int i = 0; i < 4; ++i)
    #pragma unroll
    for (int r = 0; r < 4; ++r) {
      int nl = rowBase + wr*64 + i*16 + fk*4 + r;
      float rinv = 1.0f / ls[nl];
      #pragma unroll
      for (int j = 0; j < 4; ++j) {
        int d = colBase + wc*64 + j*16 + fr;
        ab[(size_t)nl*512 + d] = f2bf(acc[i][j][r] * rinv);
      }
    }
}

// Old 128^2 bf16 scores kernel kept for the chunked fallback path.
__global__ __launch_bounds__(256) void k_scores(const u16* __restrict__ qT,
                                                const u16* __restrict__ kT,
                                                u16* __restrict__ E,
                                                float* __restrict__ lsum,
                                                long long qkStride, long long eStride,
                                                int lsStride) {
  GEMM_PROLOGUE();
  const int bz = blockIdx.z;
  const u16* q0 = qT + (size_t)bz * qkStride;
  const u16* k0 = kT + (size_t)bz * qkStride;
  u16* Eb = E + (size_t)bz * eStride;
  float* ls = lsum + (size_t)bz * lsStride;
  const int rowBase = blockIdx.y * 128, colBase = blockIdx.x * 128;
  gemm_nt_core(q0 + (size_t)rowBase*512, 512, k0 + (size_t)colBase*512, 512,
               512, As, Bs, acc);
  const float scale = 0.04419417382415922f;
  #pragma unroll
  for (int i = 0; i < 4; ++i)
    #pragma unroll
    for (int r = 0; r < 4; ++r) {
      int nl = rowBase + wr*64 + i*16 + fk*4 + r;
      float s = 0.f;
      #pragma unroll
      for (int j = 0; j < 4; ++j) {
        int m = colBase + wc*64 + j*16 + fr;
        float e = __expf(acc[i][j][r] * scale);
        Eb[(size_t)nl*4096 + m] = f2bf(e);
        s += e;
      }
      s += __shfl_xor(s, 1, 64);
      s += __shfl_xor(s, 2, 64);
      s += __shfl_xor(s, 4, 64);
      s += __shfl_xor(s, 8, 64);
      if (fr == 0) atomicAdd(&ls[nl], s);
    }
}

// bf16 PV kept for the chunked fallback path.
__global__ __launch_bounds__(256) void k_pv(const u16* __restrict__ E,
                                            const u16* __restrict__ vb,
                                            const float* __restrict__ lsum,
                                            u16* __restrict__ attnb,
                                            long long eStride, long long vStride,
                                            int lsStride, long long aStride,
                                            int doSwz) {
  GEMM_PROLOGUE();
  const int bz = blockIdx.z;
  const u16* Eb = E + (size_t)bz * eStride;
  const u16* vbb = vb + (size_t)bz * vStride;
  const float* ls = lsum + (size_t)bz * lsStride;
  u16* ab = attnb + (size_t)bz * aStride;
  int rowT = blockIdx.y, colT = blockIdx.x;
  if (doSwz) {
    int f = blockIdx.y * 4 + blockIdx.x;
    int L = (f & 7) * 16 + (f >> 3);
    rowT = L >> 2; colT = L & 3;
  }
  const int rowBase = rowT * 128, colBase = colT * 128;
  gemm_nt_core(Eb + (size_t)rowBase*4096, 4096, vbb + (size_t)colBase*4096, 4096,
               4096, As, Bs, acc);
  #pragma unroll
  for (int i = 0; i < 4; ++i)
    #pragma unroll
    for (int r = 0; r < 4; ++r) {
      int nl = rowBase + wr*64 + i*16 + fk*4 + r;
      float rinv = 1.0f / ls[nl];
      #pragma unroll
      for (int j = 0; j < 4; ++j) {
        int d = colBase + wc*64 + j*16 + fr;
        ab[(size_t)nl*512 + d] = f2bf(acc[i][j][r] * rinv);
      }
    }
}

__global__ __launch_bounds__(256) void k_proj(const u16* __restrict__ wp,
                                              const u16* __restrict__ attn,
                                              const float* __restrict__ bproj,
                                              const float* __restrict__ x,
                                              float* __restrict__ out) {
  GEMM_PROLOGUE();
  const int bz = blockIdx.z;
  const int rowBase = blockIdx.y * 128, colBase = blockIdx.x * 128;
  gemm_nt_core(wp + (size_t)rowBase*512, 512,
               attn + ((size_t)bz*4096 + colBase)*512, 512, 512, As, Bs, acc);
  #pragma unroll
  for (int i = 0; i < 4; ++i)
    #pragma unroll
    for (int j = 0; j < 4; ++j)
      #pragma unroll
      for (int r = 0; r < 4; ++r) {
        int o = rowBase + wr*64 + i*16 + fk*4 + r;
        int n = colBase + wc*64 + j*16 + fr;
        size_t idx = ((size_t)bz*512 + o)*4096 + n;
        out[idx] = acc[i][j][r] + bproj[o] + x[idx];
      }
}

extern "C" void kernel_launch(void* const* d_in, const int* in_sizes, int n_in,
                              void* d_out, int out_size, void* d_ws, size_t ws_size,
                              hipStream_t stream) {
  const float* x      = (const float*)d_in[0];
  const float* gamma  = (const float*)d_in[1];
  const float* beta   = (const float*)d_in[2];
  const float* w_qkv  = (const float*)d_in[3];
  const float* b_qkv  = (const float*)d_in[4];
  const float* w_proj = (const float*)d_in[5];
  const float* b_proj = (const float*)d_in[6];
  float* out = (float*)d_out;
  char* ws = (char*)d_ws;

  size_t off = 0;
  u16* wqb   = (u16*)(ws + off); off += (size_t)1536*512*2;
  u16* wpb   = (u16*)(ws + off); off += (size_t)512*512*2;
  float* stats = (float*)(ws + off); off += 256;
  float* psum  = (float*)(ws + off); off += 512*4;
  float* psumsq= (float*)(ws + off); off += 512*4;
  float* lsum  = (float*)(ws + off); off += (size_t)4*4096*4;
  u16* hT    = (u16*)(ws + off);                      // reused as attn_out after QKV
  u16* attn  = hT;
  off += (size_t)4*4096*512*2;
  u16* qT    = (u16*)(ws + off); off += (size_t)4*4096*512*2;
  u16* kT    = (u16*)(ws + off); off += (size_t)4*4096*512*2;
  u16* vb    = (u16*)(ws + off); off += (size_t)4*4096*512*2;
  u16* E     = (u16*)(ws + off);
  size_t avail = ws_size > off ? ws_size - off : 0;
  const size_t fullE = (size_t)4*4096*4096*2;          // bf16 worst case bound
  const int useF8 = (avail >= (size_t)4*4096*4096) ? 1 : 0;   // fp8 E needs 67 MB
  // fp8 q/k/v/E overlay the bf16 buffers (exclusive use per path)
  u8* qF8 = (u8*)qT;
  u8* kF8 = (u8*)kT;
  u8* vF8 = (u8*)vb;
  u8* E8  = (u8*)E;

  gn_stats1_k<<<512, 256, 0, stream>>>(x, psum, psumsq);
  gn_stats2_k<<<1, 32, 0, stream>>>(psum, psumsq, stats);
  gn_apply_k<<<dim3(64, 8, 4), 256, 0, stream>>>(x, gamma, beta, stats, hT);
  cast_w_k<<<3072, 256, 0, stream>>>(w_qkv, w_proj, wqb, wpb);
  k_qkv<<<dim3(12, 32, 4), 256, 0, stream>>>(hT, wqb, b_qkv, qT, kT, vb,
                                             qF8, kF8, vF8, useF8);

  if (useF8) {
    (void)hipMemsetAsync(lsum, 0, (size_t)4*4096*sizeof(float), stream);
    k_scores128_f8<<<dim3(32, 32, 4), 256, 0, stream>>>(qF8, kF8, E8, lsum);
    k_pv_f8<<<dim3(4, 32, 4), 256, 0, stream>>>(E8, vF8, lsum, attn);
  } else {
    int CH = 4096;
    while (CH > 128 && (size_t)CH*4096*2 > avail) CH >>= 1;
    for (int b = 0; b < 4; ++b) {
      for (int c0 = 0; c0 < 4096; c0 += CH) {
        (void)hipMemsetAsync(lsum, 0, (size_t)CH * sizeof(float), stream);
        k_scores<<<dim3(32, CH/128, 1), 256, 0, stream>>>(
            qT + ((size_t)b*4096 + c0)*512, kT + (size_t)b*4096*512, E, lsum, 0, 0, 0);
        k_pv<<<dim3(4, CH/128, 1), 256, 0, stream>>>(
            E, vb + (size_t)b*512*4096, lsum, attn + ((size_t)b*4096 + c0)*512, 0, 0, 0, 0, 0);
      }
    }
  }
  k_proj<<<dim3(32, 4, 4), 256, 0, stream>>>(wpb, attn, b_proj, x, out);
}

// Round 12
// 270.003 us; speedup vs baseline: 1.2120x; 1.1162x over previous
//
#include <hip/hip_runtime.h>

typedef __attribute__((ext_vector_type(8))) short bf16x8;
typedef __attribute__((ext_vector_type(4))) float f32x4;
using u16 = unsigned short;
using u8 = unsigned char;

#define DEVINL static __device__ __forceinline__

DEVINL u16 f2bf(float f) {
  union { float f; unsigned u; } v; v.f = f;
  unsigned r = v.u + 0x7FFFu + ((v.u >> 16) & 1u);   // RNE
  return (u16)(r >> 16);
}

// fp32 -> OCP e4m3fn. Software fallback (RNE, saturating, denormal-aware).
DEVINL u8 f2e4m3_sw(float f) {
  union { float f; unsigned u; } v; v.f = f;
  unsigned s = (v.u >> 24) & 0x80u;
  float a = fabsf(f);
  a = fminf(a, 448.f);
  union { float f; unsigned u; } b; b.f = a;
  unsigned bu = b.u + 0x7FFFFu + ((b.u >> 20) & 1u);   // RNE at bit 20
  unsigned e = bu >> 23;
  unsigned r;
  if (e >= 121) {
    r = ((e - 120) << 3) | ((bu >> 20) & 7u);
    if (r > 0x7Eu) r = 0x7Eu;
  } else {
    r = (unsigned)(a * 512.f + 0.5f);
    if (r > 7u) r = 8u;
  }
  return (u8)(r | s);
}

#if __has_builtin(__builtin_amdgcn_cvt_pk_fp8_f32)
// HW converter: v_cvt_pk_fp8_f32 (OCP e4m3 on gfx950). ~1 op vs ~25.
DEVINL u8 f2e4m3(float f) {
  int p = __builtin_amdgcn_cvt_pk_fp8_f32(f, f, 0, false);
  return (u8)(p & 0xFF);
}
#else
DEVINL u8 f2e4m3(float f) { return f2e4m3_sw(f); }
#endif

DEVINL void gload16(const u16* g, u16* l) {
  __builtin_amdgcn_global_load_lds((const __attribute__((address_space(1))) void*)g,
                                   (__attribute__((address_space(3))) void*)l,
                                   16, 0, 0);
}
DEVINL void gload16b(const u8* g, u8* l) {
  __builtin_amdgcn_global_load_lds((const __attribute__((address_space(1))) void*)g,
                                   (__attribute__((address_space(3))) void*)l,
                                   16, 0, 0);
}

// ---------------- GroupNorm stats: two-stage, 512-block parallel ----------------
__global__ __launch_bounds__(256) void gn_stats1_k(const float* __restrict__ x,
                                                   float* __restrict__ psum,
                                                   float* __restrict__ psumsq) {
  const int blk = blockIdx.x;
  const float4* p4 = (const float4*)(x + (size_t)(blk >> 4) * (64 * 4096))
                     + (size_t)(blk & 15) * 4096;
  float s = 0.f, ss = 0.f;
  #pragma unroll
  for (int i = 0; i < 16; ++i) {
    float4 v = p4[i*256 + threadIdx.x];
    s  += v.x + v.y + v.z + v.w;
    ss += v.x*v.x + v.y*v.y + v.z*v.z + v.w*v.w;
  }
  #pragma unroll
  for (int off = 32; off > 0; off >>= 1) {
    s  += __shfl_down(s, off, 64);
    ss += __shfl_down(ss, off, 64);
  }
  __shared__ float rs[4], rss[4];
  const int lane = threadIdx.x & 63, w = threadIdx.x >> 6;
  if (lane == 0) { rs[w] = s; rss[w] = ss; }
  __syncthreads();
  if (threadIdx.x == 0) {
    psum[blk]   = rs[0]+rs[1]+rs[2]+rs[3];
    psumsq[blk] = rss[0]+rss[1]+rss[2]+rss[3];
  }
}

__global__ void gn_stats2_k(const float* __restrict__ psum,
                            const float* __restrict__ psumsq,
                            float* __restrict__ stats) {
  const int bg = threadIdx.x;   // 32 threads
  if (bg >= 32) return;
  float s = 0.f, ss = 0.f;
  #pragma unroll
  for (int p = 0; p < 16; ++p) { s += psum[bg*16+p]; ss += psumsq[bg*16+p]; }
  const float inv = 1.f / 262144.f;
  float mean = s * inv;
  float var  = ss * inv - mean * mean;
  stats[bg*2]   = mean;
  stats[bg*2+1] = rsqrtf(var + 1e-5f);
}

// Normalize + transpose: x[b][c][n] -> hT[b][n][c] bf16.
__global__ __launch_bounds__(256) void gn_apply_k(const float* __restrict__ x,
                                                  const float* __restrict__ gamma,
                                                  const float* __restrict__ beta,
                                                  const float* __restrict__ stats,
                                                  u16* __restrict__ hT) {
  __shared__ u16 tile[64][65];
  const int b = blockIdx.z, ct = blockIdx.y, nt = blockIdx.x;
  const int t = threadIdx.x;
  const float mean = stats[(b*8 + ct)*2 + 0];
  const float rstd = stats[(b*8 + ct)*2 + 1];
  const float* xb = x + ((size_t)b*512 + (size_t)ct*64) * 4096 + nt*64;
  #pragma unroll
  for (int i = 0; i < 16; ++i) {
    int idx = i*256 + t; int cl = idx >> 6, nl = idx & 63;
    float v  = xb[(size_t)cl*4096 + nl];
    float hn = (v - mean) * rstd * gamma[ct*64 + cl] + beta[ct*64 + cl];
    tile[cl][nl] = f2bf(hn);
  }
  __syncthreads();
  u16* o = hT + ((size_t)b*4096 + (size_t)nt*64) * 512 + ct*64;
  #pragma unroll
  for (int i = 0; i < 16; ++i) {
    int idx = i*256 + t; int nl = idx >> 6, cl = idx & 63;
    o[(size_t)nl*512 + cl] = tile[cl][nl];
  }
}

__global__ __launch_bounds__(256) void cast_w_k(const float* __restrict__ wq,
                                                const float* __restrict__ wp,
                                                u16* __restrict__ wqb,
                                                u16* __restrict__ wpb) {
  int i = blockIdx.x*256 + threadIdx.x;
  if (i < 1536*512) wqb[i] = f2bf(wq[i]);
  if (i < 512*512)  wpb[i] = f2bf(wp[i]);
}

// ---------------- NT GEMM core (m97 structure, 128x128, 4 waves, bf16) ----------
DEVINL void gemm_nt_core(const u16* __restrict__ A, int lda,
                         const u16* __restrict__ B, int ldb,
                         int K, u16* As, u16* Bs, f32x4 acc[4][4]) {
  const int tid = threadIdx.x;
  const int lane = tid & 63, w = tid >> 6;
  const int wr = w >> 1, wc = w & 1;
  const int fr = lane & 15, fk = lane >> 4;
  for (int kt = 0; kt < K; kt += 64) {
    #pragma unroll
    for (int i = 0; i < 4; ++i) {
      int ch = i*256 + tid;
      int row = ch >> 3, kc = ch & 7;
      gload16(A + (size_t)row*lda + kt + kc*8, As + ch*8);
      gload16(B + (size_t)row*ldb + kt + kc*8, Bs + ch*8);
    }
    __syncthreads();
    #pragma unroll
    for (int kk = 0; kk < 2; ++kk) {
      bf16x8 af[4], bfg[4];
      #pragma unroll
      for (int i = 0; i < 4; ++i)
        af[i] = *(const bf16x8*)(As + ((wr*64 + i*16 + fr)*64 + kk*32 + fk*8));
      #pragma unroll
      for (int j = 0; j < 4; ++j)
        bfg[j] = *(const bf16x8*)(Bs + ((wc*64 + j*16 + fr)*64 + kk*32 + fk*8));
      #pragma unroll
      for (int i = 0; i < 4; ++i)
        #pragma unroll
        for (int j = 0; j < 4; ++j)
          acc[i][j] = __builtin_amdgcn_mfma_f32_16x16x32_bf16(af[i], bfg[j], acc[i][j], 0, 0, 0);
    }
    __syncthreads();
  }
}

#define GEMM_PROLOGUE() \
  __shared__ __align__(16) u16 As[128*64]; \
  __shared__ __align__(16) u16 Bs[128*64]; \
  f32x4 acc[4][4] = {}; \
  const int tid = threadIdx.x; \
  const int lane = tid & 63, w = tid >> 6; \
  const int wr = w >> 1, wc = w & 1; \
  const int fr = lane & 15, fk = lane >> 4; \
  (void)lane;

// ---------------- NT GEMM core (fp8 e4m3, 128x128 tile, BK=128, 4 waves) --------
#define MFMA8(a, b, c) __builtin_amdgcn_mfma_f32_16x16x32_fp8_fp8((a), (b), (c), 0, 0, 0)

DEVINL void gemm_nt_f8(const u8* __restrict__ A, int lda,
                       const u8* __restrict__ B, int ldb,
                       int K, u8* Af, u8* Bf, f32x4 acc[4][4]) {
  const int tid = threadIdx.x;
  const int lane = tid & 63, w = tid >> 6;
  const int wr = w >> 1, wc = w & 1;
  const int fr = lane & 15, fk = lane >> 4;
  for (int kt = 0; kt < K; kt += 128) {
    #pragma unroll
    for (int q = 0; q < 4; ++q) {
      int c = q*256 + tid;                  // 1024 chunks of 16B per plane
      int row = c >> 3, s16 = c & 7;
      int kc = s16 ^ ((row >> 1) & 7);      // inverse swizzle on global source
      gload16b(A + (size_t)row*lda + kt + kc*16, Af + c*16);
      gload16b(B + (size_t)row*ldb + kt + kc*16, Bf + c*16);
    }
    __syncthreads();
    #pragma unroll
    for (int kk = 0; kk < 4; ++kk) {
      long long a8[4], b8[4];
      #pragma unroll
      for (int i = 0; i < 4; ++i) {
        int row = wr*64 + i*16 + fr;
        int s16r = (kk*2 + (fk>>1)) ^ ((row>>1)&7);
        a8[i] = *(const long long*)(Af + row*128 + (s16r<<4) + ((fk&1)<<3));
      }
      #pragma unroll
      for (int j = 0; j < 4; ++j) {
        int row = wc*64 + j*16 + fr;
        int s16r = (kk*2 + (fk>>1)) ^ ((row>>1)&7);
        b8[j] = *(const long long*)(Bf + row*128 + (s16r<<4) + ((fk&1)<<3));
      }
      #pragma unroll
      for (int i = 0; i < 4; ++i)
        #pragma unroll
        for (int j = 0; j < 4; ++j)
          acc[i][j] = MFMA8(a8[i], b8[j], acc[i][j]);
    }
    __syncthreads();
  }
}

// QKV. useF8: q,k,v stored as fp8 e4m3 (fp8 attention path); else bf16.
__global__ __launch_bounds__(256) void k_qkv(const u16* __restrict__ hT,
                                             const u16* __restrict__ wq,
                                             const float* __restrict__ bqkv,
                                             u16* __restrict__ qT, u16* __restrict__ kT,
                                             u16* __restrict__ vb,
                                             u8* __restrict__ qF8, u8* __restrict__ kF8,
                                             u8* __restrict__ vF8, int useF8) {
  GEMM_PROLOGUE();
  const int bz = blockIdx.z;
  const int rowBase = blockIdx.y * 128, colBase = blockIdx.x * 128;
  gemm_nt_core(hT + ((size_t)bz*4096 + rowBase)*512, 512,
               wq + (size_t)colBase*512, 512, 512, As, Bs, acc);
  #pragma unroll
  for (int i = 0; i < 4; ++i)
    #pragma unroll
    for (int j = 0; j < 4; ++j)
      #pragma unroll
      for (int r = 0; r < 4; ++r) {
        int n = rowBase + wr*64 + i*16 + fk*4 + r;
        int o = colBase + wc*64 + j*16 + fr;
        float val = acc[i][j][r] + bqkv[o];
        if (useF8) {
          if (o < 512)       qF8[((size_t)bz*4096 + n)*512 + o]          = f2e4m3(val);
          else if (o < 1024) kF8[((size_t)bz*4096 + n)*512 + (o - 512)]  = f2e4m3(val);
          else               vF8[((size_t)bz*512 + (o - 1024))*4096 + n] = f2e4m3(val);
        } else {
          u16 u = f2bf(val);
          if (o < 512)       qT[((size_t)bz*4096 + n)*512 + o]          = u;
          else if (o < 1024) kT[((size_t)bz*4096 + n)*512 + (o - 512)]  = u;
          else               vb[((size_t)bz*512 + (o - 1024))*4096 + n] = u;
        }
      }
}

// ------------- Scores (fp8): 128x128 tile, BK=64 (round-10 verified core) -------
// E stored fp8 via HW converter. ~6 blocks/CU co-resident (16 KB LDS, ~76 VGPR).
__global__ __launch_bounds__(256) void k_scores128_f8(const u8* __restrict__ qF8,
                                                      const u8* __restrict__ kF8,
                                                      u8* __restrict__ E8,
                                                      float* __restrict__ lsum) {
  __shared__ __align__(16) u8 Af[128*64];   // 8 KB
  __shared__ __align__(16) u8 Bf[128*64];   // 8 KB
  f32x4 acc[4][4] = {};
  const int tid = threadIdx.x;
  const int lane = tid & 63, w = tid >> 6;
  const int wr = w >> 1, wc = w & 1;
  const int fr = lane & 15, fk = lane >> 4;
  const int bz = blockIdx.z;
  // T1: bijective XCD swizzle, 1024 blocks/slice (1024%8==0).
  int f = blockIdx.y * 32 + blockIdx.x;
  int L = (f & 7) * 128 + (f >> 3);
  const int rowBase = (L >> 5) * 128, colBase = (L & 31) * 128;
  const u8* qa = qF8 + (size_t)bz*4096*512 + (size_t)rowBase*512;
  const u8* ka = kF8 + (size_t)bz*4096*512 + (size_t)colBase*512;
  u8* Eb = E8 + (size_t)bz*4096*4096;
  float* ls = lsum + (size_t)bz*4096;

  for (int kt = 0; kt < 512; kt += 64) {
    #pragma unroll
    for (int q = 0; q < 2; ++q) {
      int c = q*256 + tid;                  // 512 chunks of 16B per plane
      int row = c >> 2, s16 = c & 3;
      int kc = s16 ^ ((row >> 1) & 3);      // inverse swizzle on global source
      gload16b(qa + (size_t)row*512 + kt + kc*16, Af + c*16);
      gload16b(ka + (size_t)row*512 + kt + kc*16, Bf + c*16);
    }
    __syncthreads();
    #pragma unroll
    for (int kk = 0; kk < 2; ++kk) {
      long long a8[4], b8[4];
      #pragma unroll
      for (int i = 0; i < 4; ++i) {
        int row = wr*64 + i*16 + fr;
        a8[i] = *(const long long*)(Af + row*64 +
                ((((kk*2 + (fk>>1)) ^ ((row>>1)&3)) << 4) | ((fk&1) << 3)));
      }
      #pragma unroll
      for (int j = 0; j < 4; ++j) {
        int row = wc*64 + j*16 + fr;
        b8[j] = *(const long long*)(Bf + row*64 +
                ((((kk*2 + (fk>>1)) ^ ((row>>1)&3)) << 4) | ((fk&1) << 3)));
      }
      #pragma unroll
      for (int i = 0; i < 4; ++i)
        #pragma unroll
        for (int j = 0; j < 4; ++j)
          acc[i][j] = MFMA8(a8[i], b8[j], acc[i][j]);
    }
    __syncthreads();
  }

  const float scale = 0.04419417382415922f;  // 512^-0.5
  #pragma unroll
  for (int i = 0; i < 4; ++i)
    #pragma unroll
    for (int r = 0; r < 4; ++r) {
      int nl = rowBase + wr*64 + i*16 + fk*4 + r;
      float s = 0.f;
      #pragma unroll
      for (int j = 0; j < 4; ++j) {
        int m = colBase + wc*64 + j*16 + fr;
        float e = __expf(acc[i][j][r] * scale);
        Eb[(size_t)nl*4096 + m] = f2e4m3(e);
        s += e;
      }
      s += __shfl_xor(s, 1, 64);
      s += __shfl_xor(s, 2, 64);
      s += __shfl_xor(s, 4, 64);
      s += __shfl_xor(s, 8, 64);
      if (fr == 0) atomicAdd(&ls[nl], s);
    }
}

// ------------- PV (fp8): out[nl][d] = (sum_m E[nl][m] * v[d][m]) / lsum[nl] -----
__global__ __launch_bounds__(256) void k_pv_f8(const u8* __restrict__ E8,
                                               const u8* __restrict__ vF8,
                                               const float* __restrict__ lsum,
                                               u16* __restrict__ attnb) {
  __shared__ __align__(16) u8 Af[128*128];   // 16 KB
  __shared__ __align__(16) u8 Bf[128*128];   // 16 KB
  f32x4 acc[4][4] = {};
  const int tid = threadIdx.x;
  const int lane = tid & 63, w = tid >> 6;
  const int wr = w >> 1, wc = w & 1;
  const int fr = lane & 15, fk = lane >> 4;
  const int bz = blockIdx.z;
  // T1: bijective XCD swizzle, 128 blocks/slice (128%8==0), grouped by E-row.
  int f = blockIdx.y * 4 + blockIdx.x;
  int L = (f & 7) * 16 + (f >> 3);
  const int rowBase = (L >> 2) * 128, colBase = (L & 3) * 128;
  const u8* Eb = E8 + (size_t)bz*4096*4096 + (size_t)rowBase*4096;
  const u8* vbb = vF8 + (size_t)bz*512*4096 + (size_t)colBase*4096;
  const float* ls = lsum + (size_t)bz*4096;
  u16* ab = attnb + (size_t)bz*4096*512;

  gemm_nt_f8(Eb, 4096, vbb, 4096, 4096, Af, Bf, acc);

  #pragma unroll
  for (int i = 0; i < 4; ++i)
    #pragma unroll
    for (int r = 0; r < 4; ++r) {
      int nl = rowBase + wr*64 + i*16 + fk*4 + r;
      float rinv = 1.0f / ls[nl];
      #pragma unroll
      for (int j = 0; j < 4; ++j) {
        int d = colBase + wc*64 + j*16 + fr;
        ab[(size_t)nl*512 + d] = f2bf(acc[i][j][r] * rinv);
      }
    }
}

// Old 128^2 bf16 scores kernel kept for the chunked fallback path.
__global__ __launch_bounds__(256) void k_scores(const u16* __restrict__ qT,
                                                const u16* __restrict__ kT,
                                                u16* __restrict__ E,
                                                float* __restrict__ lsum,
                                                long long qkStride, long long eStride,
                                                int lsStride) {
  GEMM_PROLOGUE();
  const int bz = blockIdx.z;
  const u16* q0 = qT + (size_t)bz * qkStride;
  const u16* k0 = kT + (size_t)bz * qkStride;
  u16* Eb = E + (size_t)bz * eStride;
  float* ls = lsum + (size_t)bz * lsStride;
  const int rowBase = blockIdx.y * 128, colBase = blockIdx.x * 128;
  gemm_nt_core(q0 + (size_t)rowBase*512, 512, k0 + (size_t)colBase*512, 512,
               512, As, Bs, acc);
  const float scale = 0.04419417382415922f;
  #pragma unroll
  for (int i = 0; i < 4; ++i)
    #pragma unroll
    for (int r = 0; r < 4; ++r) {
      int nl = rowBase + wr*64 + i*16 + fk*4 + r;
      float s = 0.f;
      #pragma unroll
      for (int j = 0; j < 4; ++j) {
        int m = colBase + wc*64 + j*16 + fr;
        float e = __expf(acc[i][j][r] * scale);
        Eb[(size_t)nl*4096 + m] = f2bf(e);
        s += e;
      }
      s += __shfl_xor(s, 1, 64);
      s += __shfl_xor(s, 2, 64);
      s += __shfl_xor(s, 4, 64);
      s += __shfl_xor(s, 8, 64);
      if (fr == 0) atomicAdd(&ls[nl], s);
    }
}

// bf16 PV kept for the chunked fallback path.
__global__ __launch_bounds__(256) void k_pv(const u16* __restrict__ E,
                                            const u16* __restrict__ vb,
                                            const float* __restrict__ lsum,
                                            u16* __restrict__ attnb,
                                            long long eStride, long long vStride,
                                            int lsStride, long long aStride,
                                            int doSwz) {
  GEMM_PROLOGUE();
  const int bz = blockIdx.z;
  const u16* Eb = E + (size_t)bz * eStride;
  const u16* vbb = vb + (size_t)bz * vStride;
  const float* ls = lsum + (size_t)bz * lsStride;
  u16* ab = attnb + (size_t)bz * aStride;
  int rowT = blockIdx.y, colT = blockIdx.x;
  if (doSwz) {
    int f = blockIdx.y * 4 + blockIdx.x;
    int L = (f & 7) * 16 + (f >> 3);
    rowT = L >> 2; colT = L & 3;
  }
  const int rowBase = rowT * 128, colBase = colT * 128;
  gemm_nt_core(Eb + (size_t)rowBase*4096, 4096, vbb + (size_t)colBase*4096, 4096,
               4096, As, Bs, acc);
  #pragma unroll
  for (int i = 0; i < 4; ++i)
    #pragma unroll
    for (int r = 0; r < 4; ++r) {
      int nl = rowBase + wr*64 + i*16 + fk*4 + r;
      float rinv = 1.0f / ls[nl];
      #pragma unroll
      for (int j = 0; j < 4; ++j) {
        int d = colBase + wc*64 + j*16 + fr;
        ab[(size_t)nl*512 + d] = f2bf(acc[i][j][r] * rinv);
      }
    }
}

__global__ __launch_bounds__(256) void k_proj(const u16* __restrict__ wp,
                                              const u16* __restrict__ attn,
                                              const float* __restrict__ bproj,
                                              const float* __restrict__ x,
                                              float* __restrict__ out) {
  GEMM_PROLOGUE();
  const int bz = blockIdx.z;
  const int rowBase = blockIdx.y * 128, colBase = blockIdx.x * 128;
  gemm_nt_core(wp + (size_t)rowBase*512, 512,
               attn + ((size_t)bz*4096 + colBase)*512, 512, 512, As, Bs, acc);
  #pragma unroll
  for (int i = 0; i < 4; ++i)
    #pragma unroll
    for (int j = 0; j < 4; ++j)
      #pragma unroll
      for (int r = 0; r < 4; ++r) {
        int o = rowBase + wr*64 + i*16 + fk*4 + r;
        int n = colBase + wc*64 + j*16 + fr;
        size_t idx = ((size_t)bz*512 + o)*4096 + n;
        out[idx] = acc[i][j][r] + bproj[o] + x[idx];
      }
}

extern "C" void kernel_launch(void* const* d_in, const int* in_sizes, int n_in,
                              void* d_out, int out_size, void* d_ws, size_t ws_size,
                              hipStream_t stream) {
  const float* x      = (const float*)d_in[0];
  const float* gamma  = (const float*)d_in[1];
  const float* beta   = (const float*)d_in[2];
  const float* w_qkv  = (const float*)d_in[3];
  const float* b_qkv  = (const float*)d_in[4];
  const float* w_proj = (const float*)d_in[5];
  const float* b_proj = (const float*)d_in[6];
  float* out = (float*)d_out;
  char* ws = (char*)d_ws;

  size_t off = 0;
  u16* wqb   = (u16*)(ws + off); off += (size_t)1536*512*2;
  u16* wpb   = (u16*)(ws + off); off += (size_t)512*512*2;
  float* stats = (float*)(ws + off); off += 256;
  float* psum  = (float*)(ws + off); off += 512*4;
  float* psumsq= (float*)(ws + off); off += 512*4;
  float* lsum  = (float*)(ws + off); off += (size_t)4*4096*4;
  u16* hT    = (u16*)(ws + off);                      // reused as attn_out after QKV
  u16* attn  = hT;
  off += (size_t)4*4096*512*2;
  u16* qT    = (u16*)(ws + off); off += (size_t)4*4096*512*2;
  u16* kT    = (u16*)(ws + off); off += (size_t)4*4096*512*2;
  u16* vb    = (u16*)(ws + off); off += (size_t)4*4096*512*2;
  u16* E     = (u16*)(ws + off);
  size_t avail = ws_size > off ? ws_size - off : 0;
  const int useF8 = (avail >= (size_t)4*4096*4096) ? 1 : 0;   // fp8 E needs 67 MB
  // fp8 q/k/v/E overlay the bf16 buffers (exclusive use per path)
  u8* qF8 = (u8*)qT;
  u8* kF8 = (u8*)kT;
  u8* vF8 = (u8*)vb;
  u8* E8  = (u8*)E;

  gn_stats1_k<<<512, 256, 0, stream>>>(x, psum, psumsq);
  gn_stats2_k<<<1, 32, 0, stream>>>(psum, psumsq, stats);
  gn_apply_k<<<dim3(64, 8, 4), 256, 0, stream>>>(x, gamma, beta, stats, hT);
  cast_w_k<<<3072, 256, 0, stream>>>(w_qkv, w_proj, wqb, wpb);
  k_qkv<<<dim3(12, 32, 4), 256, 0, stream>>>(hT, wqb, b_qkv, qT, kT, vb,
                                             qF8, kF8, vF8, useF8);

  if (useF8) {
    (void)hipMemsetAsync(lsum, 0, (size_t)4*4096*sizeof(float), stream);
    k_scores128_f8<<<dim3(32, 32, 4), 256, 0, stream>>>(qF8, kF8, E8, lsum);
    k_pv_f8<<<dim3(4, 32, 4), 256, 0, stream>>>(E8, vF8, lsum, attn);
  } else {
    int CH = 4096;
    while (CH > 128 && (size_t)CH*4096*2 > avail) CH >>= 1;
    for (int b = 0; b < 4; ++b) {
      for (int c0 = 0; c0 < 4096; c0 += CH) {
        (void)hipMemsetAsync(lsum, 0, (size_t)CH * sizeof(float), stream);
        k_scores<<<dim3(32, CH/128, 1), 256, 0, stream>>>(
            qT + ((size_t)b*4096 + c0)*512, kT + (size_t)b*4096*512, E, lsum, 0, 0, 0);
        k_pv<<<dim3(4, CH/128, 1), 256, 0, stream>>>(
            E, vb + (size_t)b*512*4096, lsum, attn + ((size_t)b*4096 + c0)*512, 0, 0, 0, 0, 0);
      }
    }
  }
  k_proj<<<dim3(32, 4, 4), 256, 0, stream>>>(wpb, attn, b_proj, x, out);
}